// Round 1
// baseline (9504.288 us; speedup 1.0000x reference)
//
#include <hip/hip_runtime.h>
#include <math.h>

// GGNNRel forward, fp32 baseline with algebraic restructuring.
// R=2048 NODE=53 H=512 C=51 T=3.  RN = R*NODE = 108544 (divisible by 128).
//
// Key identities (see analysis): av1 rows identical = row[r]@hidden[r,2:];
// av2 = outer(row[r], h0+h1); concat([av,av],-1)@W.T == av@(W[:,:512]+W[:,512:]).T.
// => per (r, gate): u_g = a1@Weff_g.T, t_g = s@Weff_g.T; node<2 uses u_g,
// node>=2 uses row[r,node-2]*t_g.
//
// ws layout (floats): hbuf RN*512 | zv RN*512 (reused as out_lin) | g RN*512 |
// as1 4096*512 | UT 4096*1536 | rowb R*51 | Weff 1536*512  => ~672 MB total.
// hidden is updated IN-PLACE from iter 2 on (epilogue reads fh only at its own
// output coordinates), so only one hidden buffer is needed.

#define R_    2048
#define NODE_ 53
#define H2_   512
#define C_    51
#define NOBJ_ 151
#define RN_   (R_*NODE_)    // 108544
#define K27_  (NODE_*512)   // 27136

#define BM  128
#define BN  128
#define BKt 16
#define LLD 132  // BM + 4 pad, keeps float4 alignment (132%4==0)

__device__ __forceinline__ float sigmoidf_(float x){ return 1.f/(1.f+__expf(-x)); }

// XCD-aware swizzle: contiguous logical chunk per XCD (requires nwg%8==0 — all
// our grids satisfy this). Logical id is m-major so one XCD sees all n-tiles of
// an m-range -> A-tiles hit that XCD's L2.
__device__ __forceinline__ int xcd_swz(int bid, int nwg){
  int chunk = nwg >> 3;
  return (bid & 7) * chunk + (bid >> 3);
}

// C[m][n] = sum_k A[m][k] * W[n][k]   (i.e. A @ W.T), W row-major (N,K).
// SPLIT: A switches from A0 to A1 at k==512 (for the output stage concat).
template<bool SPLIT>
__device__ __forceinline__ void gemm_core(const float* __restrict__ A0,
                                          const float* __restrict__ A1,
                                          const float* __restrict__ W,
                                          int lda, int ldw, int K,
                                          long m0, long n0,
                                          float acc[8][8])
{
  __shared__ float As[BKt][LLD];
  __shared__ float Bs[BKt][LLD];
  const int tid = threadIdx.x;
  const int lr = tid >> 1;          // 0..127 : row within tile for global loads
  const int lc = (tid & 1) << 3;    // 0 or 8 : k-offset for global loads
  const int tx = tid & 15;
  const int ty = tid >> 4;
#pragma unroll
  for (int i=0;i<8;i++)
#pragma unroll
    for (int j=0;j<8;j++) acc[i][j] = 0.f;

  for (int k0=0; k0<K; k0+=BKt){
    const float* Ap = A0; int ka = k0;
    if (SPLIT && k0 >= 512){ Ap = A1; ka = k0 - 512; }
    const float* ap = Ap + (m0+lr)*(long)lda + ka + lc;
    const float* wp = W  + (n0+lr)*(long)ldw + k0 + lc;
    float4 a0 = *(const float4*)(ap);
    float4 a1 = *(const float4*)(ap+4);
    float4 b0 = *(const float4*)(wp);
    float4 b1 = *(const float4*)(wp+4);
    __syncthreads();  // protect previous iteration's LDS reads
    As[lc+0][lr]=a0.x; As[lc+1][lr]=a0.y; As[lc+2][lr]=a0.z; As[lc+3][lr]=a0.w;
    As[lc+4][lr]=a1.x; As[lc+5][lr]=a1.y; As[lc+6][lr]=a1.z; As[lc+7][lr]=a1.w;
    Bs[lc+0][lr]=b0.x; Bs[lc+1][lr]=b0.y; Bs[lc+2][lr]=b0.z; Bs[lc+3][lr]=b0.w;
    Bs[lc+4][lr]=b1.x; Bs[lc+5][lr]=b1.y; Bs[lc+6][lr]=b1.z; Bs[lc+7][lr]=b1.w;
    __syncthreads();
#pragma unroll
    for (int kk=0;kk<BKt;kk++){
      float a[8], b[8];
      *(float4*)(a  ) = *(const float4*)&As[kk][ty<<3];
      *(float4*)(a+4) = *(const float4*)&As[kk][(ty<<3)+4];
      *(float4*)(b  ) = *(const float4*)&Bs[kk][tx<<3];
      *(float4*)(b+4) = *(const float4*)&Bs[kk][(tx<<3)+4];
#pragma unroll
      for (int i=0;i<8;i++)
#pragma unroll
        for (int j=0;j<8;j++) acc[i][j] = fmaf(a[i], b[j], acc[i][j]);
    }
  }
}

// ---- prep: gather row[r] = matrix[s0,s1], fold gate weights -------------
extern "C" __global__ void k_prep_row(const int* __restrict__ preds,
                                      const float* __restrict__ matrix,
                                      float* __restrict__ rowb)
{
  int idx = blockIdx.x*256 + threadIdx.x;
  if (idx >= R_*C_) return;
  int r = idx / C_;
  int c = idx - r*C_;
  int s0 = preds[2*r], s1 = preds[2*r+1];
  rowb[idx] = matrix[((long)s0*NOBJ_ + s1)*C_ + c];
}

extern "C" __global__ void k_prep_weff(const float* __restrict__ w3w,
                                       const float* __restrict__ w4w,
                                       const float* __restrict__ w5w,
                                       float* __restrict__ Weff)
{
  int idx = blockIdx.x*256 + threadIdx.x;        // 3*512*512 = 786432 exact
  if (idx >= 3*512*512) return;
  int g   = idx >> 18;
  int rem = idx & 0x3FFFF;
  int o   = rem >> 9;
  int k   = rem & 511;
  const float* w = (g==0) ? w3w : (g==1) ? w4w : w5w;
  Weff[idx] = w[o*1024 + k] + w[o*1024 + 512 + k];
}

// ---- per-iteration: a1 = row . hidden[2:], s = h0+h1 --------------------
extern "C" __global__ void __launch_bounds__(256,1)
k_as1(const float* __restrict__ fh, const float* __restrict__ rowb,
      float* __restrict__ as1)
{
  int r = blockIdx.x;
  const float* h  = fh + (long)r*NODE_*512;
  const float* rw = rowb + r*C_;
#pragma unroll 1
  for (int rep=0; rep<2; rep++){
    int col = threadIdx.x + (rep<<8);
    float s = h[col] + h[512 + col];
    float a = 0.f;
#pragma unroll 17
    for (int c=0;c<C_;c++)
      a = fmaf(rw[c], h[(2+c)*512 + col], a);
    as1[((long)2*r  )*512 + col] = a;
    as1[((long)2*r+1)*512 + col] = s;
  }
}

// ---- UT = as1 @ WeffAll.T :  (4096,512)@(512,1536) ----------------------
// UT[2r][g*512+o] = u_g[r][o],  UT[2r+1][g*512+o] = t_g[r][o]
extern "C" __global__ void __launch_bounds__(256,2)
k_gemm_ut(const float* __restrict__ as1, const float* __restrict__ Weff,
          float* __restrict__ UT)
{
  const int nnt = 1536/BN;                 // 12
  int lid = xcd_swz(blockIdx.x, gridDim.x);
  long m0 = (long)(lid / nnt) * BM;
  long n0 = (long)(lid % nnt) * BN;
  float acc[8][8];
  gemm_core<false>(as1, nullptr, Weff, 512, 512, 512, m0, n0, acc);
  const int tx = threadIdx.x & 15, ty = threadIdx.x >> 4;
#pragma unroll
  for (int i=0;i<8;i++){
    long rn = m0 + (ty<<3) + i;
    float4 v0, v1;
    v0.x=acc[i][0]; v0.y=acc[i][1]; v0.z=acc[i][2]; v0.w=acc[i][3];
    v1.x=acc[i][4]; v1.y=acc[i][5]; v1.z=acc[i][6]; v1.w=acc[i][7];
    *(float4*)(UT + rn*1536 + n0 + (tx<<3)    ) = v0;
    *(float4*)(UT + rn*1536 + n0 + (tx<<3) + 4) = v1;
  }
}

// ---- stage Z/R: acc = fh @ {w3u|w4u}.T, epilogue -> zv and g=rv*fh ------
extern "C" __global__ void __launch_bounds__(256,2)
k_gemm_zr(const float* __restrict__ fh,
          const float* __restrict__ w3u, const float* __restrict__ w4u,
          const float* __restrict__ UT,  const float* __restrict__ rowb,
          const float* __restrict__ b3w, const float* __restrict__ b3u,
          const float* __restrict__ b4w, const float* __restrict__ b4u,
          float* __restrict__ zv, float* __restrict__ gbuf)
{
  const int nnt = 1024/BN;                 // 8 (logical N = two gates)
  int lid = xcd_swz(blockIdx.x, gridDim.x);
  long m0 = (long)(lid / nnt) * BM;
  int  nt = lid % nnt;
  int  side = nt >> 2;                     // 0: z-gate, 1: r-gate
  long n0l = (long)(nt & 3) * BN;          // local col base within gate
  const float* W = side ? w4u : w3u;
  float acc[8][8];
  gemm_core<false>(fh, nullptr, W, 512, 512, 512, m0, n0l, acc);

  const int tx = threadIdx.x & 15, ty = threadIdx.x >> 4;
  int o0 = (int)n0l + (tx<<3);
  const float* bW = side ? b4w : b3w;
  const float* bU = side ? b4u : b3u;
  float bb[8];
#pragma unroll
  for (int j=0;j<8;j++) bb[j] = bW[o0+j] + bU[o0+j];
  int goff = side ? 512 : 0;
#pragma unroll
  for (int i=0;i<8;i++){
    long rn = m0 + (ty<<3) + i;
    int r  = (int)(rn / 53);
    int nd = (int)(rn - (long)r*53);
    bool isU = nd < 2;
    float scale = isU ? 1.f : rowb[r*C_ + nd - 2];
    const float* up = UT + ((long)2*r + (isU?0:1))*1536 + goff + o0;
    if (side == 0){
      float* zp = zv + rn*512 + o0;
#pragma unroll
      for (int j=0;j<8;j++)
        zp[j] = sigmoidf_(acc[i][j] + scale*up[j] + bb[j]);
    } else {
      const float* fp = fh + rn*512 + o0;
      float* gp = gbuf + rn*512 + o0;
#pragma unroll
      for (int j=0;j<8;j++)
        gp[j] = sigmoidf_(acc[i][j] + scale*up[j] + bb[j]) * fp[j];
    }
  }
}

// ---- stage H: acc = g @ w5u.T, epilogue -> fh_out (in-place safe) -------
extern "C" __global__ void __launch_bounds__(256,2)
k_gemm_h(const float* __restrict__ gbuf, const float* __restrict__ w5u,
         const float* __restrict__ UT,   const float* __restrict__ rowb,
         const float* __restrict__ b5w,  const float* __restrict__ b5u,
         const float* __restrict__ zv,   const float* __restrict__ fh_in,
         float* __restrict__ fh_out)
{
  const int nnt = 512/BN;                  // 4
  int lid = xcd_swz(blockIdx.x, gridDim.x);
  long m0 = (long)(lid / nnt) * BM;
  long n0 = (long)(lid % nnt) * BN;
  float acc[8][8];
  gemm_core<false>(gbuf, nullptr, w5u, 512, 512, 512, m0, n0, acc);

  const int tx = threadIdx.x & 15, ty = threadIdx.x >> 4;
  int o0 = (int)n0 + (tx<<3);
  float bb[8];
#pragma unroll
  for (int j=0;j<8;j++) bb[j] = b5w[o0+j] + b5u[o0+j];
#pragma unroll
  for (int i=0;i<8;i++){
    long rn = m0 + (ty<<3) + i;
    int r  = (int)(rn / 53);
    int nd = (int)(rn - (long)r*53);
    bool isU = nd < 2;
    float scale = isU ? 1.f : rowb[r*C_ + nd - 2];
    const float* up = UT + ((long)2*r + (isU?0:1))*1536 + 1024 + o0;
    const float* zp = zv    + rn*512 + o0;
    const float* fp = fh_in + rn*512 + o0;
    float*       op = fh_out+ rn*512 + o0;
#pragma unroll
    for (int j=0;j<8;j++){
      float hv = tanhf(acc[i][j] + scale*up[j] + bb[j]);
      float z  = zp[j];
      op[j] = (1.f - z)*fp[j] + z*hv;
    }
  }
}

// ---- output: out_lin = relu([hidden|input] @ wo.T + bo) -----------------
extern "C" __global__ void __launch_bounds__(256,2)
k_gemm_o(const float* __restrict__ fh, const float* __restrict__ inp,
         const float* __restrict__ wo, const float* __restrict__ bo,
         float* __restrict__ outl)
{
  const int nnt = 512/BN;                  // 4
  int lid = xcd_swz(blockIdx.x, gridDim.x);
  long m0 = (long)(lid / nnt) * BM;
  long n0 = (long)(lid % nnt) * BN;
  float acc[8][8];
  gemm_core<true>(fh, inp, wo, 512, 1024, 1024, m0, n0, acc);

  const int tx = threadIdx.x & 15, ty = threadIdx.x >> 4;
  int o0 = (int)n0 + (tx<<3);
  float bb[8];
#pragma unroll
  for (int j=0;j<8;j++) bb[j] = bo[o0+j];
#pragma unroll
  for (int i=0;i<8;i++){
    long rn = m0 + (ty<<3) + i;
    float* op = outl + rn*512 + o0;
#pragma unroll
    for (int j=0;j<8;j++)
      op[j] = fmaxf(acc[i][j] + bb[j], 0.f);
  }
}

// ---- rel_dists = out_lin.reshape(R,27136) @ wc.T + bc -------------------
extern "C" __global__ void k_rel_init(const float* __restrict__ bc,
                                      float* __restrict__ dout)
{
  int idx = blockIdx.x*256 + threadIdx.x;
  if (idx >= R_*C_) return;
  dout[idx] = bc[idx % C_];
}

#define RG_KB 64
#define RG_CH (K27_/8)   // 3392
extern "C" __global__ void __launch_bounds__(256,2)
k_rel_gemm(const float* __restrict__ outl, const float* __restrict__ wc,
           float* __restrict__ dout)
{
  __shared__ float sw[C_][68];             // 68: float4-aligned padded stride
  int r0    = blockIdx.x * 32;
  int kbase = blockIdx.y * RG_CH;
  int tid = threadIdx.x;
  int c  = tid & 63;
  int mr = tid >> 6;                       // 0..3, rows mr*8..mr*8+7
  float acc[8];
#pragma unroll
  for (int i=0;i<8;i++) acc[i]=0.f;

  for (int k0=kbase; k0<kbase+RG_CH; k0+=RG_KB){
    __syncthreads();
    for (int idx=tid; idx<C_*RG_KB; idx+=256){
      int cr = idx >> 6, ck = idx & 63;
      sw[cr][ck] = wc[(long)cr*K27_ + k0 + ck];
    }
    __syncthreads();
    if (c < C_){
#pragma unroll
      for (int i=0;i<8;i++){
        long m = r0 + (mr<<3) + i;
        const float* op = outl + m*(long)K27_ + k0;
#pragma unroll
        for (int kk=0;kk<RG_KB;kk+=4){
          float4 a = *(const float4*)(op + kk);       // wave-uniform broadcast
          float4 w = *(const float4*)&sw[c][kk];
          acc[i] = fmaf(a.x, w.x, acc[i]);
          acc[i] = fmaf(a.y, w.y, acc[i]);
          acc[i] = fmaf(a.z, w.z, acc[i]);
          acc[i] = fmaf(a.w, w.w, acc[i]);
        }
      }
    }
  }
  if (c < C_){
#pragma unroll
    for (int i=0;i<8;i++){
      int m = r0 + (mr<<3) + i;
      atomicAdd(&dout[m*C_ + c], acc[i]);
    }
  }
}

// -------------------------------------------------------------------------
extern "C" void kernel_launch(void* const* d_in, const int* in_sizes, int n_in,
                              void* d_out, int out_size, void* d_ws, size_t ws_size,
                              hipStream_t stream)
{
  const int*   preds = (const int*)  d_in[1];
  const float* input = (const float*)d_in[2];
  const float* matrix= (const float*)d_in[4];
  const float* w3w=(const float*)d_in[5],  *b3w=(const float*)d_in[6];
  const float* w3u=(const float*)d_in[7],  *b3u=(const float*)d_in[8];
  const float* w4w=(const float*)d_in[9],  *b4w=(const float*)d_in[10];
  const float* w4u=(const float*)d_in[11], *b4u=(const float*)d_in[12];
  const float* w5w=(const float*)d_in[13], *b5w=(const float*)d_in[14];
  const float* w5u=(const float*)d_in[15], *b5u=(const float*)d_in[16];
  const float* wo =(const float*)d_in[17], *bo =(const float*)d_in[18];
  const float* wc =(const float*)d_in[19], *bc =(const float*)d_in[20];
  float* dout = (float*)d_out;

  char* ws = (char*)d_ws;
  size_t off = 0;
  auto alloc = [&](size_t nfl){ float* p = (float*)(ws + off); off += nfl*sizeof(float); return p; };
  float* hbuf = alloc((size_t)RN_*512);
  float* zv   = alloc((size_t)RN_*512);
  float* gbuf = alloc((size_t)RN_*512);
  float* as1  = alloc((size_t)4096*512);
  float* UT   = alloc((size_t)4096*1536);
  float* rowb = alloc((size_t)R_*C_);
  float* Weff = alloc((size_t)1536*512);
  float* outl = zv;  // zv dead after the T loop; reuse for out_lin

  k_prep_row <<<(R_*C_+255)/256, 256, 0, stream>>>(preds, matrix, rowb);
  k_prep_weff<<<(3*512*512)/256, 256, 0, stream>>>(w3w, w4w, w5w, Weff);

  for (int t=0;t<3;t++){
    const float* fh = (t==0) ? input : hbuf;
    k_as1    <<<R_, 256, 0, stream>>>(fh, rowb, as1);
    k_gemm_ut<<<(4096/BM)*(1536/BN), 256, 0, stream>>>(as1, Weff, UT);
    k_gemm_zr<<<(RN_/BM)*(1024/BN), 256, 0, stream>>>(fh, w3u, w4u, UT, rowb,
                                                      b3w,b3u,b4w,b4u, zv, gbuf);
    k_gemm_h <<<(RN_/BM)*(512/BN), 256, 0, stream>>>(gbuf, w5u, UT, rowb,
                                                     b5w, b5u, zv, fh, hbuf);
  }
  k_gemm_o  <<<(RN_/BM)*(512/BN), 256, 0, stream>>>(hbuf, input, wo, bo, outl);
  k_rel_init<<<(R_*C_+255)/256, 256, 0, stream>>>(bc, dout);
  k_rel_gemm<<<dim3(R_/32, 8), 256, 0, stream>>>(outl, wc, dout);
}

// Round 2
// 3855.555 us; speedup vs baseline: 2.4651x; 2.4651x over previous
//
#include <hip/hip_runtime.h>
#include <hip/hip_bf16.h>
#include <math.h>

// GGNNRel forward, round 2: big GEMMs moved to bf16 MFMA (m97 structure:
// 128x128 tile, BK=32, 4 waves x (4x4 of 16x16x32), global_load_lds width-16,
// linear LDS, 2 barriers/K-step, XCD swizzle).
// Precision plan: A/B operands bf16; accum fp32 (MFMA); zv + UT + final K=27136
// reduction stay fp32. Fallback if absmax fails: hi/lo split-bf16 3-pass MFMA.
//
// Algebraic identities (round 1, verified): av1 rows = row[r]@h[2:];
// av2 = outer(row, h0+h1); concat([av,av],-1)@W.T == av@(W[:,:512]+W[:,512:]).T
// => per gate g: u_g = a1@Weff_g.T, t_g = s@Weff_g.T; node<2 -> u_g,
//    node>=2 -> row[r,node-2]*t_g  (UT buffer, added in GEMM epilogues).

#define R_    2048
#define NODE_ 53
#define C_    51
#define NOBJ_ 151
#define RN_   (R_*NODE_)    // 108544 = 128*848
#define K27_  (NODE_*512)   // 27136

typedef __hip_bfloat16 bf16;
typedef __attribute__((ext_vector_type(8))) short bf16x8;
typedef __attribute__((ext_vector_type(4))) float f32x4;

__device__ __forceinline__ float sigmoidf_(float x){ return 1.f/(1.f+__expf(-x)); }

// XCD-aware swizzle (all grids %8==0): contiguous m-major chunk per XCD.
__device__ __forceinline__ int xcd_swz(int bid, int nwg){
  int chunk = nwg >> 3;
  return (bid & 7) * chunk + (bid >> 3);
}

__device__ __forceinline__ void gld_lds16(const void* g, void* l){
  __builtin_amdgcn_global_load_lds(
      (const __attribute__((address_space(1))) void*)g,
      (__attribute__((address_space(3))) void*)l, 16, 0, 0);
}

// C[m][n] = sum_k A[m][k]*W[n][k]; A row-major (M,lda), W row-major (N,ldw),
// both bf16. SPLIT: A switches A0->A1 at k==512 (output-stage concat).
// 128x128 tile, 256 threads = 4 waves (2x2), per-wave 64x64 = 4x4 frags.
template<bool SPLIT>
__device__ __forceinline__ void mfma_core(const bf16* __restrict__ A0,
                                          const bf16* __restrict__ A1,
                                          const bf16* __restrict__ W,
                                          int lda, int ldw, int K,
                                          int m0, int n0, f32x4 acc[4][4])
{
  __shared__ short As[128*32];   // [row][k] linear, row stride 64 B
  __shared__ short Bs[128*32];
  const int tid = threadIdx.x;
  const int wv = tid >> 6, l = tid & 63;
  const int lr = l & 15, kq = l >> 4;
  const int wr = wv >> 1, wc = wv & 1;
#pragma unroll
  for (int i=0;i<4;i++)
#pragma unroll
    for (int j=0;j<4;j++) acc[i][j] = (f32x4){0.f,0.f,0.f,0.f};

  // staging: issue j covers tile rows [j*64, j*64+64); wave wv owns 16 rows;
  // lane l -> row wv*16 + (l>>2), 16B chunk (l&3). LDS dest = wave-uniform
  // base + lane*16 (HW semantics), which matches linear [128][32] layout.
  const int srow = wv*16 + (l>>2);
  const int skb  = (l&3)*16;
  char* Asb = (char*)As;
  char* Bsb = (char*)Bs;

  for (int k0=0; k0<K; k0+=32){
    const bf16* Ap = A0; int ka = k0;
    if (SPLIT && k0 >= 512){ Ap = A1; ka = k0-512; }
    const char* ga = (const char*)(Ap + (long)(m0+srow)*lda + ka) + skb;
    const char* gw = (const char*)(W  + (long)(n0+srow)*ldw + k0) + skb;
    gld_lds16(ga,                   Asb + wv*1024);
    gld_lds16(ga + (long)64*lda*2,  Asb + 4096 + wv*1024);
    gld_lds16(gw,                   Bsb + wv*1024);
    gld_lds16(gw + (long)64*ldw*2,  Bsb + 4096 + wv*1024);
    __syncthreads();                 // drains vmcnt (async LDS loads) + lgkm
    bf16x8 af[4], bfv[4];
#pragma unroll
    for (int i=0;i<4;i++){
      af[i]  = *(const bf16x8*)(Asb + (wr*64 + i*16 + lr)*64 + kq*16);
      bfv[i] = *(const bf16x8*)(Bsb + (wc*64 + i*16 + lr)*64 + kq*16);
    }
#pragma unroll
    for (int i=0;i<4;i++)
#pragma unroll
      for (int j=0;j<4;j++)
        acc[i][j] = __builtin_amdgcn_mfma_f32_16x16x32_bf16(af[i], bfv[j], acc[i][j], 0, 0, 0);
    __syncthreads();                 // protect LDS from next stage overwrite
  }
}
// C/D layout (m89/m91 verified): col = n0+wc*64+j*16+(l&15),
//                                row = m0+wr*64+i*16+(l>>4)*4+reg.

// ---- prep ---------------------------------------------------------------
extern "C" __global__ void k_prep_row(const int* __restrict__ preds,
                                      const float* __restrict__ matrix,
                                      float* __restrict__ rowb)
{
  int idx = blockIdx.x*256 + threadIdx.x;
  if (idx >= R_*C_) return;
  int r = idx / C_;
  int c = idx - r*C_;
  int s0 = preds[2*r], s1 = preds[2*r+1];
  rowb[idx] = matrix[((long)s0*NOBJ_ + s1)*C_ + c];
}

extern "C" __global__ void k_prep_weff(const float* __restrict__ w3w,
                                       const float* __restrict__ w4w,
                                       const float* __restrict__ w5w,
                                       bf16* __restrict__ weffb)
{
  int idx = blockIdx.x*256 + threadIdx.x;        // 3*512*512
  if (idx >= 3*512*512) return;
  int g   = idx >> 18;
  int rem = idx & 0x3FFFF;
  int o   = rem >> 9;
  int k   = rem & 511;
  const float* w = (g==0) ? w3w : (g==1) ? w4w : w5w;
  weffb[idx] = __float2bfloat16(w[o*1024 + k] + w[o*1024 + 512 + k]);
}

extern "C" __global__ void k_f2b(const float* __restrict__ s,
                                 bf16* __restrict__ d, int n)
{
  int i = (blockIdx.x*256 + threadIdx.x)*4;
  if (i >= n) return;
  float4 v = *(const float4*)(s+i);
  d[i  ] = __float2bfloat16(v.x);
  d[i+1] = __float2bfloat16(v.y);
  d[i+2] = __float2bfloat16(v.z);
  d[i+3] = __float2bfloat16(v.w);
}

// ---- per-iteration: a1 = row . h[2:], s = h0+h1 (bf16 in/out) -----------
extern "C" __global__ void __launch_bounds__(256)
k_as1(const bf16* __restrict__ fh, const float* __restrict__ rowb,
      bf16* __restrict__ as1b)
{
  int r = blockIdx.x;
  const bf16* h  = fh + (long)r*NODE_*512;
  const float* rw = rowb + r*C_;
#pragma unroll 1
  for (int rep=0; rep<2; rep++){
    int col = threadIdx.x + (rep<<8);
    float s = __bfloat162float(h[col]) + __bfloat162float(h[512 + col]);
    float a = 0.f;
#pragma unroll 17
    for (int c=0;c<C_;c++)
      a = fmaf(rw[c], __bfloat162float(h[(2+c)*512 + col]), a);
    as1b[(2*r  )*512 + col] = __float2bfloat16(a);
    as1b[(2*r+1)*512 + col] = __float2bfloat16(s);
  }
}

// ---- UT = as1 @ WeffAll.T : (4096,512)@(512,1536), fp32 out -------------
extern "C" __global__ void __launch_bounds__(256)
k_gemm_ut(const bf16* __restrict__ as1b, const bf16* __restrict__ weffb,
          float* __restrict__ UT)
{
  const int nnt = 1536/128;                // 12
  int lid = xcd_swz(blockIdx.x, gridDim.x);
  int m0 = (lid / nnt) * 128;
  int n0 = (lid % nnt) * 128;
  f32x4 acc[4][4];
  mfma_core<false>(as1b, nullptr, weffb, 512, 512, 512, m0, n0, acc);
  const int wv = threadIdx.x >> 6, l = threadIdx.x & 63;
  const int wr = wv >> 1, wc = wv & 1;
#pragma unroll
  for (int i=0;i<4;i++){
    int rbase = m0 + wr*64 + i*16 + (l>>4)*4;
#pragma unroll
    for (int j=0;j<4;j++){
      int col = n0 + wc*64 + j*16 + (l&15);
#pragma unroll
      for (int rg=0; rg<4; rg++)
        UT[(rbase+rg)*1536 + col] = acc[i][j][rg];
    }
  }
}

// ---- stage Z/R: acc = fh @ {w3u|w4u}.T + UT-term, fused epilogue --------
extern "C" __global__ void __launch_bounds__(256)
k_gemm_zr(const bf16* __restrict__ fh, const bf16* __restrict__ wub,
          const float* __restrict__ UT, const float* __restrict__ rowb,
          const float* __restrict__ b3w, const float* __restrict__ b3u,
          const float* __restrict__ b4w, const float* __restrict__ b4u,
          float* __restrict__ zv, bf16* __restrict__ gb)
{
  const int nnt = 1024/128;                // 8 (cols 0-511: z, 512-1023: r)
  int lid = xcd_swz(blockIdx.x, gridDim.x);
  int m0 = (lid / nnt) * 128;
  int n0 = (lid % nnt) * 128;
  f32x4 acc[4][4];
  mfma_core<false>(fh, nullptr, wub, 512, 512, 512, m0, n0, acc);

  const int wv = threadIdx.x >> 6, l = threadIdx.x & 63;
  const int wr = wv >> 1, wc = wv & 1;
  const int side = n0 >> 9;                // block-uniform (128 | 512)
  const float* bW = side ? b4w : b3w;
  const float* bU = side ? b4u : b3u;
#pragma unroll
  for (int i=0;i<4;i++){
    int rbase = m0 + wr*64 + i*16 + (l>>4)*4;
#pragma unroll
    for (int j=0;j<4;j++){
      int col = n0 + wc*64 + j*16 + (l&15);
      int o   = col & 511;
      float bb = bW[o] + bU[o];
#pragma unroll
      for (int rg=0; rg<4; rg++){
        int rn = rbase + rg;
        int r  = rn / 53, nd = rn - r*53;
        float scale = (nd<2) ? 1.f : rowb[r*C_ + nd - 2];
        int   e     = (nd<2) ? 0 : 1;
        float up = UT[(2*r+e)*1536 + col];
        float v  = acc[i][j][rg] + scale*up + bb;
        int idx = rn*512 + o;
        if (side == 0){
          zv[idx] = sigmoidf_(v);
        } else {
          gb[idx] = __float2bfloat16(sigmoidf_(v) * __bfloat162float(fh[idx]));
        }
      }
    }
  }
}

// ---- stage H: acc = g @ w5u.T, epilogue -> h update (in-place bf16) -----
extern "C" __global__ void __launch_bounds__(256)
k_gemm_h(const bf16* __restrict__ gbuf, const bf16* __restrict__ w5ub,
         const float* __restrict__ UT,  const float* __restrict__ rowb,
         const float* __restrict__ b5w, const float* __restrict__ b5u,
         const float* __restrict__ zv,  const bf16* __restrict__ fh_in,
         bf16* __restrict__ hb)
{
  const int nnt = 512/128;                 // 4
  int lid = xcd_swz(blockIdx.x, gridDim.x);
  int m0 = (lid / nnt) * 128;
  int n0 = (lid % nnt) * 128;
  f32x4 acc[4][4];
  mfma_core<false>(gbuf, nullptr, w5ub, 512, 512, 512, m0, n0, acc);

  const int wv = threadIdx.x >> 6, l = threadIdx.x & 63;
  const int wr = wv >> 1, wc = wv & 1;
#pragma unroll
  for (int i=0;i<4;i++){
    int rbase = m0 + wr*64 + i*16 + (l>>4)*4;
#pragma unroll
    for (int j=0;j<4;j++){
      int col = n0 + wc*64 + j*16 + (l&15);
      float bb = b5w[col] + b5u[col];
#pragma unroll
      for (int rg=0; rg<4; rg++){
        int rn = rbase + rg;
        int r  = rn / 53, nd = rn - r*53;
        float scale = (nd<2) ? 1.f : rowb[r*C_ + nd - 2];
        int   e     = (nd<2) ? 0 : 1;
        float up = UT[(2*r+e)*1536 + 1024 + col];
        float hv = tanhf(acc[i][j][rg] + scale*up + bb);
        int idx = rn*512 + col;
        float z  = zv[idx];
        float fv = __bfloat162float(fh_in[idx]);
        hb[idx] = __float2bfloat16((1.f - z)*fv + z*hv);
      }
    }
  }
}

// ---- output: out_lin = relu([h | input] @ wo.T + bo), fp32 out ----------
extern "C" __global__ void __launch_bounds__(256)
k_gemm_o(const bf16* __restrict__ hb, const bf16* __restrict__ inb,
         const bf16* __restrict__ wob, const float* __restrict__ bo,
         float* __restrict__ outl)
{
  const int nnt = 512/128;                 // 4
  int lid = xcd_swz(blockIdx.x, gridDim.x);
  int m0 = (lid / nnt) * 128;
  int n0 = (lid % nnt) * 128;
  f32x4 acc[4][4];
  mfma_core<true>(hb, inb, wob, 512, 1024, 1024, m0, n0, acc);

  const int wv = threadIdx.x >> 6, l = threadIdx.x & 63;
  const int wr = wv >> 1, wc = wv & 1;
#pragma unroll
  for (int i=0;i<4;i++){
    int rbase = m0 + wr*64 + i*16 + (l>>4)*4;
#pragma unroll
    for (int j=0;j<4;j++){
      int col = n0 + wc*64 + j*16 + (l&15);
      float bb = bo[col];
#pragma unroll
      for (int rg=0; rg<4; rg++){
        int rn = rbase + rg;
        outl[rn*512 + col] = fmaxf(acc[i][j][rg] + bb, 0.f);
      }
    }
  }
}

// ---- rel_dists = out_lin.reshape(R,27136) @ wc.T + bc (fp32, unchanged) --
extern "C" __global__ void k_rel_init(const float* __restrict__ bc,
                                      float* __restrict__ dout)
{
  int idx = blockIdx.x*256 + threadIdx.x;
  if (idx >= R_*C_) return;
  dout[idx] = bc[idx % C_];
}

#define RG_KB 64
#define RG_CH (K27_/8)   // 3392
extern "C" __global__ void __launch_bounds__(256)
k_rel_gemm(const float* __restrict__ outl, const float* __restrict__ wc,
           float* __restrict__ dout)
{
  __shared__ float sw[C_][68];
  int r0    = blockIdx.x * 32;
  int kbase = blockIdx.y * RG_CH;
  int tid = threadIdx.x;
  int c  = tid & 63;
  int mr = tid >> 6;
  float acc[8];
#pragma unroll
  for (int i=0;i<8;i++) acc[i]=0.f;

  for (int k0=kbase; k0<kbase+RG_CH; k0+=RG_KB){
    __syncthreads();
    for (int idx=tid; idx<C_*RG_KB; idx+=256){
      int cr = idx >> 6, ck = idx & 63;
      sw[cr][ck] = wc[(long)cr*K27_ + k0 + ck];
    }
    __syncthreads();
    if (c < C_){
#pragma unroll
      for (int i=0;i<8;i++){
        long m = r0 + (mr<<3) + i;
        const float* op = outl + m*(long)K27_ + k0;
#pragma unroll
        for (int kk=0;kk<RG_KB;kk+=4){
          float4 a = *(const float4*)(op + kk);
          float4 w = *(const float4*)&sw[c][kk];
          acc[i] = fmaf(a.x, w.x, acc[i]);
          acc[i] = fmaf(a.y, w.y, acc[i]);
          acc[i] = fmaf(a.z, w.z, acc[i]);
          acc[i] = fmaf(a.w, w.w, acc[i]);
        }
      }
    }
  }
  if (c < C_){
#pragma unroll
    for (int i=0;i<8;i++){
      int m = r0 + (mr<<3) + i;
      atomicAdd(&dout[m*C_ + c], acc[i]);
    }
  }
}

// -------------------------------------------------------------------------
extern "C" void kernel_launch(void* const* d_in, const int* in_sizes, int n_in,
                              void* d_out, int out_size, void* d_ws, size_t ws_size,
                              hipStream_t stream)
{
  const int*   preds = (const int*)  d_in[1];
  const float* input = (const float*)d_in[2];
  const float* matrix= (const float*)d_in[4];
  const float* w3w=(const float*)d_in[5],  *b3w=(const float*)d_in[6];
  const float* w3u=(const float*)d_in[7],  *b3u=(const float*)d_in[8];
  const float* w4w=(const float*)d_in[9],  *b4w=(const float*)d_in[10];
  const float* w4u=(const float*)d_in[11], *b4u=(const float*)d_in[12];
  const float* w5w=(const float*)d_in[13], *b5w=(const float*)d_in[14];
  const float* w5u=(const float*)d_in[15], *b5u=(const float*)d_in[16];
  const float* wo =(const float*)d_in[17], *bo =(const float*)d_in[18];
  const float* wc =(const float*)d_in[19], *bc =(const float*)d_in[20];
  float* dout = (float*)d_out;

  char* ws = (char*)d_ws;
  size_t off = 0;
  auto alloc = [&](size_t bytes){
    void* p = ws + off;
    off += (bytes + 255) & ~(size_t)255;
    return p;
  };
  bf16*  hb    = (bf16*) alloc((size_t)RN_*512*2);     // 111 MB
  bf16*  inb   = (bf16*) alloc((size_t)RN_*512*2);     // 111 MB
  float* zv    = (float*)alloc((size_t)RN_*512*4);     // 222 MB (reused: outl)
  bf16*  gb    = (bf16*) alloc((size_t)RN_*512*2);     // 111 MB
  bf16*  as1b  = (bf16*) alloc((size_t)4096*512*2);
  float* UT    = (float*)alloc((size_t)4096*1536*4);   // 25 MB
  float* rowb  = (float*)alloc((size_t)R_*C_*4);
  bf16*  weffb = (bf16*) alloc((size_t)1536*512*2);
  bf16*  wub   = (bf16*) alloc((size_t)1024*512*2);    // [w3u ; w4u]
  bf16*  w5ub  = (bf16*) alloc((size_t)512*512*2);
  bf16*  wob   = (bf16*) alloc((size_t)512*1024*2);
  float* outl  = zv;

  // prep
  k_prep_row <<<(R_*C_+255)/256, 256, 0, stream>>>(preds, matrix, rowb);
  k_prep_weff<<<(3*512*512)/256, 256, 0, stream>>>(w3w, w4w, w5w, weffb);
  k_f2b<<<((RN_*512/4)+255)/256, 256, 0, stream>>>(input, inb, RN_*512);
  k_f2b<<<((512*512/4)+255)/256, 256, 0, stream>>>(w3u, wub, 512*512);
  k_f2b<<<((512*512/4)+255)/256, 256, 0, stream>>>(w4u, wub + 512*512, 512*512);
  k_f2b<<<((512*512/4)+255)/256, 256, 0, stream>>>(w5u, w5ub, 512*512);
  k_f2b<<<((512*1024/4)+255)/256, 256, 0, stream>>>(wo, wob, 512*1024);

  for (int t=0;t<3;t++){
    const bf16* fh = (t==0) ? inb : hb;
    k_as1    <<<R_, 256, 0, stream>>>(fh, rowb, as1b);
    k_gemm_ut<<<(4096/128)*(1536/128), 256, 0, stream>>>(as1b, weffb, UT);
    k_gemm_zr<<<(RN_/128)*(1024/128), 256, 0, stream>>>(fh, wub, UT, rowb,
                                                        b3w,b3u,b4w,b4u, zv, gb);
    k_gemm_h <<<(RN_/128)*(512/128), 256, 0, stream>>>(gb, w5ub, UT, rowb,
                                                       b5w, b5u, zv, fh, hb);
  }
  k_gemm_o  <<<(RN_/128)*(512/128), 256, 0, stream>>>(hb, inb, wob, bo, outl);
  k_rel_init<<<(R_*C_+255)/256, 256, 0, stream>>>(bc, dout);
  k_rel_gemm<<<dim3(R_/32, 8), 256, 0, stream>>>(outl, wc, dout);
}

// Round 4
// 3149.001 us; speedup vs baseline: 3.0182x; 1.2244x over previous
//
#include <hip/hip_runtime.h>
#include <hip/hip_bf16.h>
#include <math.h>

// GGNNRel forward, round 3 resubmit (round-3 bench died on container
// acquisition, not on the kernel — source unchanged to keep the A/B clean).
// Changes vs round 2: k_rel_gemm rewritten as fp32 LDS-tiled GEMM (was 746us:
// wave-uniform broadcast A-reads + 8-way LDS conflicts + 24% occupancy);
// zv stored bf16. Big GEMMs stay m97-structure bf16 MFMA.
//
// Algebraic identities (round 1, verified): av1 rows = row[r]@h[2:];
// av2 = outer(row, h0+h1); concat([av,av],-1)@W.T == av@(W[:,:512]+W[:,512:]).T
// => per gate g: u_g = a1@Weff_g.T, t_g = s@Weff_g.T; node<2 -> u_g,
//    node>=2 -> row[r,node-2]*t_g  (UT buffer, added in GEMM epilogues).

#define R_    2048
#define NODE_ 53
#define C_    51
#define NOBJ_ 151
#define RN_   (R_*NODE_)    // 108544 = 128*848
#define K27_  (NODE_*512)   // 27136

typedef __hip_bfloat16 bf16;
typedef __attribute__((ext_vector_type(8))) short bf16x8;
typedef __attribute__((ext_vector_type(4))) float f32x4;

__device__ __forceinline__ float sigmoidf_(float x){ return 1.f/(1.f+__expf(-x)); }

// XCD-aware swizzle (all grids %8==0): contiguous m-major chunk per XCD.
__device__ __forceinline__ int xcd_swz(int bid, int nwg){
  int chunk = nwg >> 3;
  return (bid & 7) * chunk + (bid >> 3);
}

__device__ __forceinline__ void gld_lds16(const void* g, void* l){
  __builtin_amdgcn_global_load_lds(
      (const __attribute__((address_space(1))) void*)g,
      (__attribute__((address_space(3))) void*)l, 16, 0, 0);
}

// C[m][n] = sum_k A[m][k]*W[n][k]; A row-major (M,lda), W row-major (N,ldw),
// both bf16. SPLIT: A switches A0->A1 at k==512 (output-stage concat).
// 128x128 tile, 256 threads = 4 waves (2x2), per-wave 64x64 = 4x4 frags.
template<bool SPLIT>
__device__ __forceinline__ void mfma_core(const bf16* __restrict__ A0,
                                          const bf16* __restrict__ A1,
                                          const bf16* __restrict__ W,
                                          int lda, int ldw, int K,
                                          int m0, int n0, f32x4 acc[4][4])
{
  __shared__ short As[128*32];   // [row][k] linear, row stride 64 B
  __shared__ short Bs[128*32];
  const int tid = threadIdx.x;
  const int wv = tid >> 6, l = tid & 63;
  const int lr = l & 15, kq = l >> 4;
  const int wr = wv >> 1, wc = wv & 1;
#pragma unroll
  for (int i=0;i<4;i++)
#pragma unroll
    for (int j=0;j<4;j++) acc[i][j] = (f32x4){0.f,0.f,0.f,0.f};

  const int srow = wv*16 + (l>>2);
  const int skb  = (l&3)*16;
  char* Asb = (char*)As;
  char* Bsb = (char*)Bs;

  for (int k0=0; k0<K; k0+=32){
    const bf16* Ap = A0; int ka = k0;
    if (SPLIT && k0 >= 512){ Ap = A1; ka = k0-512; }
    const char* ga = (const char*)(Ap + (long)(m0+srow)*lda + ka) + skb;
    const char* gw = (const char*)(W  + (long)(n0+srow)*ldw + k0) + skb;
    gld_lds16(ga,                   Asb + wv*1024);
    gld_lds16(ga + (long)64*lda*2,  Asb + 4096 + wv*1024);
    gld_lds16(gw,                   Bsb + wv*1024);
    gld_lds16(gw + (long)64*ldw*2,  Bsb + 4096 + wv*1024);
    __syncthreads();                 // drains vmcnt (async LDS loads) + lgkm
    bf16x8 af[4], bfv[4];
#pragma unroll
    for (int i=0;i<4;i++){
      af[i]  = *(const bf16x8*)(Asb + (wr*64 + i*16 + lr)*64 + kq*16);
      bfv[i] = *(const bf16x8*)(Bsb + (wc*64 + i*16 + lr)*64 + kq*16);
    }
#pragma unroll
    for (int i=0;i<4;i++)
#pragma unroll
      for (int j=0;j<4;j++)
        acc[i][j] = __builtin_amdgcn_mfma_f32_16x16x32_bf16(af[i], bfv[j], acc[i][j], 0, 0, 0);
    __syncthreads();                 // protect LDS from next stage overwrite
  }
}
// C/D layout (m89/m91 verified): col = n0+wc*64+j*16+(l&15),
//                                row = m0+wr*64+i*16+(l>>4)*4+reg.

// ---- prep ---------------------------------------------------------------
extern "C" __global__ void k_prep_row(const int* __restrict__ preds,
                                      const float* __restrict__ matrix,
                                      float* __restrict__ rowb)
{
  int idx = blockIdx.x*256 + threadIdx.x;
  if (idx >= R_*C_) return;
  int r = idx / C_;
  int c = idx - r*C_;
  int s0 = preds[2*r], s1 = preds[2*r+1];
  rowb[idx] = matrix[((long)s0*NOBJ_ + s1)*C_ + c];
}

extern "C" __global__ void k_prep_weff(const float* __restrict__ w3w,
                                       const float* __restrict__ w4w,
                                       const float* __restrict__ w5w,
                                       bf16* __restrict__ weffb)
{
  int idx = blockIdx.x*256 + threadIdx.x;        // 3*512*512
  if (idx >= 3*512*512) return;
  int g   = idx >> 18;
  int rem = idx & 0x3FFFF;
  int o   = rem >> 9;
  int k   = rem & 511;
  const float* w = (g==0) ? w3w : (g==1) ? w4w : w5w;
  weffb[idx] = __float2bfloat16(w[o*1024 + k] + w[o*1024 + 512 + k]);
}

extern "C" __global__ void k_f2b(const float* __restrict__ s,
                                 bf16* __restrict__ d, int n)
{
  int i = (blockIdx.x*256 + threadIdx.x)*4;
  if (i >= n) return;
  float4 v = *(const float4*)(s+i);
  d[i  ] = __float2bfloat16(v.x);
  d[i+1] = __float2bfloat16(v.y);
  d[i+2] = __float2bfloat16(v.z);
  d[i+3] = __float2bfloat16(v.w);
}

// wc[51][27136] -> wcT[27136][64] (cols 51..63 zero), tile-transposed via LDS
extern "C" __global__ void __launch_bounds__(256)
k_wct(const float* __restrict__ wc, float* __restrict__ wcT)
{
  __shared__ float sm[C_][65];
  int k0 = blockIdx.x * 64;
  int t = threadIdx.x;
  for (int idx = t; idx < C_*64; idx += 256){
    int c = idx >> 6, k = idx & 63;
    sm[c][k] = wc[(long)c*K27_ + k0 + k];
  }
  __syncthreads();
  for (int idx = t; idx < 64*64; idx += 256){
    int k = idx >> 6, c = idx & 63;
    wcT[(long)(k0+k)*64 + c] = (c < C_) ? sm[c][k] : 0.f;
  }
}

// ---- per-iteration: a1 = row . h[2:], s = h0+h1 (bf16 in/out) -----------
extern "C" __global__ void __launch_bounds__(256)
k_as1(const bf16* __restrict__ fh, const float* __restrict__ rowb,
      bf16* __restrict__ as1b)
{
  int r = blockIdx.x;
  const bf16* h  = fh + (long)r*NODE_*512;
  const float* rw = rowb + r*C_;
#pragma unroll 1
  for (int rep=0; rep<2; rep++){
    int col = threadIdx.x + (rep<<8);
    float s = __bfloat162float(h[col]) + __bfloat162float(h[512 + col]);
    float a = 0.f;
#pragma unroll 17
    for (int c=0;c<C_;c++)
      a = fmaf(rw[c], __bfloat162float(h[(2+c)*512 + col]), a);
    as1b[(2*r  )*512 + col] = __float2bfloat16(a);
    as1b[(2*r+1)*512 + col] = __float2bfloat16(s);
  }
}

// ---- UT = as1 @ WeffAll.T : (4096,512)@(512,1536), fp32 out -------------
extern "C" __global__ void __launch_bounds__(256)
k_gemm_ut(const bf16* __restrict__ as1b, const bf16* __restrict__ weffb,
          float* __restrict__ UT)
{
  const int nnt = 1536/128;                // 12
  int lid = xcd_swz(blockIdx.x, gridDim.x);
  int m0 = (lid / nnt) * 128;
  int n0 = (lid % nnt) * 128;
  f32x4 acc[4][4];
  mfma_core<false>(as1b, nullptr, weffb, 512, 512, 512, m0, n0, acc);
  const int wv = threadIdx.x >> 6, l = threadIdx.x & 63;
  const int wr = wv >> 1, wc = wv & 1;
#pragma unroll
  for (int i=0;i<4;i++){
    int rbase = m0 + wr*64 + i*16 + (l>>4)*4;
#pragma unroll
    for (int j=0;j<4;j++){
      int col = n0 + wc*64 + j*16 + (l&15);
#pragma unroll
      for (int rg=0; rg<4; rg++)
        UT[(rbase+rg)*1536 + col] = acc[i][j][rg];
    }
  }
}

// ---- stage Z/R: acc = fh @ {w3u|w4u}.T + UT-term, fused epilogue --------
extern "C" __global__ void __launch_bounds__(256)
k_gemm_zr(const bf16* __restrict__ fh, const bf16* __restrict__ wub,
          const float* __restrict__ UT, const float* __restrict__ rowb,
          const float* __restrict__ b3w, const float* __restrict__ b3u,
          const float* __restrict__ b4w, const float* __restrict__ b4u,
          bf16* __restrict__ zvb, bf16* __restrict__ gb)
{
  const int nnt = 1024/128;                // 8 (cols 0-511: z, 512-1023: r)
  int lid = xcd_swz(blockIdx.x, gridDim.x);
  int m0 = (lid / nnt) * 128;
  int n0 = (lid % nnt) * 128;
  f32x4 acc[4][4];
  mfma_core<false>(fh, nullptr, wub, 512, 512, 512, m0, n0, acc);

  const int wv = threadIdx.x >> 6, l = threadIdx.x & 63;
  const int wr = wv >> 1, wc = wv & 1;
  const int side = n0 >> 9;                // block-uniform (128 | 512)
  const float* bW = side ? b4w : b3w;
  const float* bU = side ? b4u : b3u;
#pragma unroll
  for (int i=0;i<4;i++){
    int rbase = m0 + wr*64 + i*16 + (l>>4)*4;
#pragma unroll
    for (int j=0;j<4;j++){
      int col = n0 + wc*64 + j*16 + (l&15);
      int o   = col & 511;
      float bb = bW[o] + bU[o];
#pragma unroll
      for (int rg=0; rg<4; rg++){
        int rn = rbase + rg;
        int r  = rn / 53, nd = rn - r*53;
        float scale = (nd<2) ? 1.f : rowb[r*C_ + nd - 2];
        int   e     = (nd<2) ? 0 : 1;
        float up = UT[(2*r+e)*1536 + col];
        float v  = acc[i][j][rg] + scale*up + bb;
        int idx = rn*512 + o;
        if (side == 0){
          zvb[idx] = __float2bfloat16(sigmoidf_(v));
        } else {
          gb[idx] = __float2bfloat16(sigmoidf_(v) * __bfloat162float(fh[idx]));
        }
      }
    }
  }
}

// ---- stage H: acc = g @ w5u.T, epilogue -> h update (in-place bf16) -----
extern "C" __global__ void __launch_bounds__(256)
k_gemm_h(const bf16* __restrict__ gbuf, const bf16* __restrict__ w5ub,
         const float* __restrict__ UT,  const float* __restrict__ rowb,
         const float* __restrict__ b5w, const float* __restrict__ b5u,
         const bf16* __restrict__ zvb,  const bf16* __restrict__ fh_in,
         bf16* __restrict__ hb)
{
  const int nnt = 512/128;                 // 4
  int lid = xcd_swz(blockIdx.x, gridDim.x);
  int m0 = (lid / nnt) * 128;
  int n0 = (lid % nnt) * 128;
  f32x4 acc[4][4];
  mfma_core<false>(gbuf, nullptr, w5ub, 512, 512, 512, m0, n0, acc);

  const int wv = threadIdx.x >> 6, l = threadIdx.x & 63;
  const int wr = wv >> 1, wc = wv & 1;
#pragma unroll
  for (int i=0;i<4;i++){
    int rbase = m0 + wr*64 + i*16 + (l>>4)*4;
#pragma unroll
    for (int j=0;j<4;j++){
      int col = n0 + wc*64 + j*16 + (l&15);
      float bb = b5w[col] + b5u[col];
#pragma unroll
      for (int rg=0; rg<4; rg++){
        int rn = rbase + rg;
        int r  = rn / 53, nd = rn - r*53;
        float scale = (nd<2) ? 1.f : rowb[r*C_ + nd - 2];
        int   e     = (nd<2) ? 0 : 1;
        float up = UT[(2*r+e)*1536 + 1024 + col];
        float hv = tanhf(acc[i][j][rg] + scale*up + bb);
        int idx = rn*512 + col;
        float z  = __bfloat162float(zvb[idx]);
        float fv = __bfloat162float(fh_in[idx]);
        hb[idx] = __float2bfloat16((1.f - z)*fv + z*hv);
      }
    }
  }
}

// ---- output: out_lin = relu([h | input] @ wo.T + bo), fp32 out ----------
extern "C" __global__ void __launch_bounds__(256)
k_gemm_o(const bf16* __restrict__ hb, const bf16* __restrict__ inb,
         const bf16* __restrict__ wob, const float* __restrict__ bo,
         float* __restrict__ outl)
{
  const int nnt = 512/128;                 // 4
  int lid = xcd_swz(blockIdx.x, gridDim.x);
  int m0 = (lid / nnt) * 128;
  int n0 = (lid % nnt) * 128;
  f32x4 acc[4][4];
  mfma_core<true>(hb, inb, wob, 512, 1024, 1024, m0, n0, acc);

  const int wv = threadIdx.x >> 6, l = threadIdx.x & 63;
  const int wr = wv >> 1, wc = wv & 1;
#pragma unroll
  for (int i=0;i<4;i++){
    int rbase = m0 + wr*64 + i*16 + (l>>4)*4;
#pragma unroll
    for (int j=0;j<4;j++){
      int col = n0 + wc*64 + j*16 + (l&15);
      float bb = bo[col];
#pragma unroll
      for (int rg=0; rg<4; rg++){
        int rn = rbase + rg;
        outl[rn*512 + col] = fmaxf(acc[i][j][rg] + bb, 0.f);
      }
    }
  }
}

// ---- rel_dists = out_lin.reshape(R,27136) @ wc.T + bc -------------------
extern "C" __global__ void k_rel_init(const float* __restrict__ bc,
                                      float* __restrict__ dout)
{
  int idx = blockIdx.x*256 + threadIdx.x;
  if (idx >= R_*C_) return;
  dout[idx] = bc[idx % C_];
}

// fp32 LDS-tiled: block = 32 rows x 64-k steps, 8 k-chunks (y). Each thread
// owns 4 rows x 2 cols. A-reads: b128 broadcast (2 addrs/wave). W-reads: b64,
// lanes span even cols -> 2-way (free). Staging coalesced; As pad 68 (+4
// bank-shift/row). VALU floor ~45us.
#define RELKCH (K27_/8)   // 3392 = 53*64
extern "C" __global__ void __launch_bounds__(256)
k_rel_gemm(const float* __restrict__ outl, const float* __restrict__ wcT,
           float* __restrict__ dout)
{
  __shared__ float As[32][68];
  __shared__ float Ws[64][64];
  const int r0    = blockIdx.x * 32;
  const int kbase = blockIdx.y * RELKCH;
  const int t  = threadIdx.x;
  const int c0 = (t & 31) * 2;
  const int rg = t >> 5;                   // 0..7 -> rows rg*4..rg*4+3
  float acc[4][2];
#pragma unroll
  for (int i=0;i<4;i++){ acc[i][0]=0.f; acc[i][1]=0.f; }

  for (int k0=0; k0<RELKCH; k0+=64){
    __syncthreads();                       // protect previous step's reads
#pragma unroll
    for (int i=0;i<8;i++){                 // A: 32x64 = 2048 f4, 8/thread
      int f4  = i*256 + t;
      int row = f4 >> 4;
      int kf  = (f4 & 15) << 2;
      float4 v = *(const float4*)(outl + (long)(r0+row)*K27_ + kbase + k0 + kf);
      *(float4*)&As[row][kf] = v;
    }
#pragma unroll
    for (int i=0;i<4;i++){                 // W: 64x64 = 1024 f4, 4/thread
      int f4 = i*256 + t;
      int kk = f4 >> 4;
      int cf = (f4 & 15) << 2;
      *(float4*)&Ws[kk][cf] = *(const float4*)(wcT + (long)(kbase+k0+kk)*64 + cf);
    }
    __syncthreads();
#pragma unroll
    for (int k=0;k<64;k+=4){
      float4 a0 = *(const float4*)&As[rg*4+0][k];
      float4 a1 = *(const float4*)&As[rg*4+1][k];
      float4 a2 = *(const float4*)&As[rg*4+2][k];
      float4 a3 = *(const float4*)&As[rg*4+3][k];
#pragma unroll
      for (int j=0;j<4;j++){
        float2 w = *(const float2*)&Ws[k+j][c0];
        float aj0 = (&a0.x)[j], aj1 = (&a1.x)[j], aj2 = (&a2.x)[j], aj3 = (&a3.x)[j];
        acc[0][0] = fmaf(aj0, w.x, acc[0][0]);
        acc[0][1] = fmaf(aj0, w.y, acc[0][1]);
        acc[1][0] = fmaf(aj1, w.x, acc[1][0]);
        acc[1][1] = fmaf(aj1, w.y, acc[1][1]);
        acc[2][0] = fmaf(aj2, w.x, acc[2][0]);
        acc[2][1] = fmaf(aj2, w.y, acc[2][1]);
        acc[3][0] = fmaf(aj3, w.x, acc[3][0]);
        acc[3][1] = fmaf(aj3, w.y, acc[3][1]);
      }
    }
  }
#pragma unroll
  for (int i=0;i<4;i++){
    int m = r0 + rg*4 + i;
    if (c0   < C_) atomicAdd(&dout[m*C_ + c0  ], acc[i][0]);
    if (c0+1 < C_) atomicAdd(&dout[m*C_ + c0+1], acc[i][1]);
  }
}

// -------------------------------------------------------------------------
extern "C" void kernel_launch(void* const* d_in, const int* in_sizes, int n_in,
                              void* d_out, int out_size, void* d_ws, size_t ws_size,
                              hipStream_t stream)
{
  const int*   preds = (const int*)  d_in[1];
  const float* input = (const float*)d_in[2];
  const float* matrix= (const float*)d_in[4];
  const float* w3w=(const float*)d_in[5],  *b3w=(const float*)d_in[6];
  const float* w3u=(const float*)d_in[7],  *b3u=(const float*)d_in[8];
  const float* w4w=(const float*)d_in[9],  *b4w=(const float*)d_in[10];
  const float* w4u=(const float*)d_in[11], *b4u=(const float*)d_in[12];
  const float* w5w=(const float*)d_in[13], *b5w=(const float*)d_in[14];
  const float* w5u=(const float*)d_in[15], *b5u=(const float*)d_in[16];
  const float* wo =(const float*)d_in[17], *bo =(const float*)d_in[18];
  const float* wc =(const float*)d_in[19], *bc =(const float*)d_in[20];
  float* dout = (float*)d_out;

  char* ws = (char*)d_ws;
  size_t off = 0;
  auto alloc = [&](size_t bytes){
    void* p = ws + off;
    off += (bytes + 255) & ~(size_t)255;
    return p;
  };
  bf16*  hb    = (bf16*) alloc((size_t)RN_*512*2);     // 111 MB
  bf16*  inb   = (bf16*) alloc((size_t)RN_*512*2);     // 111 MB
  bf16*  zvb   = (bf16*) alloc((size_t)RN_*512*2);     // 111 MB  (adjacent..
  bf16*  gb    = (bf16*) alloc((size_t)RN_*512*2);     // 111 MB   ..to zvb)
  bf16*  as1b  = (bf16*) alloc((size_t)4096*512*2);
  float* UT    = (float*)alloc((size_t)4096*1536*4);   // 25 MB
  float* rowb  = (float*)alloc((size_t)R_*C_*4);
  float* wcT   = (float*)alloc((size_t)K27_*64*4);     // 6.9 MB
  bf16*  weffb = (bf16*) alloc((size_t)1536*512*2);
  bf16*  wub   = (bf16*) alloc((size_t)1024*512*2);    // [w3u ; w4u]
  bf16*  w5ub  = (bf16*) alloc((size_t)512*512*2);
  bf16*  wob   = (bf16*) alloc((size_t)512*1024*2);
  // outl (fp32, 222 MB) aliases zvb+gb (both dead once the T loop finishes;
  // the two bf16 allocs are contiguous and 256B-aligned).
  float* outl  = (float*)zvb;

  // prep
  k_prep_row <<<(R_*C_+255)/256, 256, 0, stream>>>(preds, matrix, rowb);
  k_prep_weff<<<(3*512*512)/256, 256, 0, stream>>>(w3w, w4w, w5w, weffb);
  k_wct<<<K27_/64, 256, 0, stream>>>(wc, wcT);
  k_f2b<<<((RN_*512/4)+255)/256, 256, 0, stream>>>(input, inb, RN_*512);
  k_f2b<<<((512*512/4)+255)/256, 256, 0, stream>>>(w3u, wub, 512*512);
  k_f2b<<<((512*512/4)+255)/256, 256, 0, stream>>>(w4u, wub + 512*512, 512*512);
  k_f2b<<<((512*512/4)+255)/256, 256, 0, stream>>>(w5u, w5ub, 512*512);
  k_f2b<<<((512*1024/4)+255)/256, 256, 0, stream>>>(wo, wob, 512*1024);

  for (int t=0;t<3;t++){
    const bf16* fh = (t==0) ? inb : hb;
    k_as1    <<<R_, 256, 0, stream>>>(fh, rowb, as1b);
    k_gemm_ut<<<(4096/128)*(1536/128), 256, 0, stream>>>(as1b, weffb, UT);
    k_gemm_zr<<<(RN_/128)*(1024/128), 256, 0, stream>>>(fh, wub, UT, rowb,
                                                        b3w,b3u,b4w,b4u, zvb, gb);
    k_gemm_h <<<(RN_/128)*(512/128), 256, 0, stream>>>(gb, w5ub, UT, rowb,
                                                       b5w, b5u, zvb, fh, hb);
  }
  k_gemm_o  <<<(RN_/128)*(512/128), 256, 0, stream>>>(hb, inb, wob, bo, outl);
  k_rel_init<<<(R_*C_+255)/256, 256, 0, stream>>>(bc, dout);
  k_rel_gemm<<<dim3(R_/32, 8), 256, 0, stream>>>(outl, wcT, dout);
}

// Round 6
// 2467.177 us; speedup vs baseline: 3.8523x; 1.2764x over previous
//
#include <hip/hip_runtime.h>
#include <hip/hip_bf16.h>
#include <math.h>

// GGNNRel forward, round 5 resubmit (round-5 bench died on GPU acquisition,
// not on the kernel — source unchanged to keep the A/B clean).
// Round-5 changes vs round 4: swapped-operand MFMA epilogues.
// mfma(W_frag, fh_frag) puts output-feature dim o in the reg dim ->
// per-thread: 4 rn-divisions (was 16), float4 UT loads (was 64 scalar),
// contiguous bf16x4/float4 stores (was 64x2B column-strided).
// Also: k_as1 vectorized bf16x8 (was scalar), k_f2b bf16x8, fast tanh.
//
// Algebraic identities (round 1, verified): av1 rows = row[r]@h[2:];
// av2 = outer(row, h0+h1); concat([av,av],-1)@W.T == av@(W[:,:512]+W[:,512:]).T
// => per gate g: u_g = a1@Weff_g.T, t_g = s@Weff_g.T; node<2 -> u_g,
//    node>=2 -> row[r,node-2]*t_g  (UT buffer, added in GEMM epilogues).

#define R_    2048
#define NODE_ 53
#define C_    51
#define NOBJ_ 151
#define RN_   (R_*NODE_)    // 108544 = 128*848
#define K27_  (NODE_*512)   // 27136

typedef __hip_bfloat16 bf16;
typedef __attribute__((ext_vector_type(8))) short bf16x8;
typedef __attribute__((ext_vector_type(4))) short bf16x4;
typedef __attribute__((ext_vector_type(4))) float f32x4;

__device__ __forceinline__ float sigmoidf_(float x){ return 1.f/(1.f+__expf(-x)); }
__device__ __forceinline__ float tanhf_(float x){ return 2.f/(1.f+__expf(-2.f*x)) - 1.f; }
__device__ __forceinline__ float b2f(short s){
  union{float f; unsigned u;} x; x.u = ((unsigned)(unsigned short)s)<<16; return x.f;
}
__device__ __forceinline__ short f2bs(float f){
  __hip_bfloat16 h = __float2bfloat16(f);
  return *reinterpret_cast<short*>(&h);
}

// XCD-aware swizzle (all grids %8==0): contiguous m-major chunk per XCD.
__device__ __forceinline__ int xcd_swz(int bid, int nwg){
  int chunk = nwg >> 3;
  return (bid & 7) * chunk + (bid >> 3);
}

__device__ __forceinline__ void gld_lds16(const void* g, void* l){
  __builtin_amdgcn_global_load_lds(
      (const __attribute__((address_space(1))) void*)g,
      (__attribute__((address_space(3))) void*)l, 16, 0, 0);
}

// acc[i][j] = sum_k W[o][k]*A[rn][k] with SWAPPED operands:
//   D row-dim = o  : og = n0 + wc*64 + i*16 + (l>>4)*4 + rg
//   D col-dim = rn : rn = m0 + wr*64 + j*16 + (l&15)
// A row-major (M=rn, lda), W row-major (N=o, ldw), both bf16.
// SPLIT: A switches A0->A1 at k==512 (output-stage concat).
template<bool SPLIT>
__device__ __forceinline__ void mfma_core(const bf16* __restrict__ A0,
                                          const bf16* __restrict__ A1,
                                          const bf16* __restrict__ W,
                                          int lda, int ldw, int K,
                                          int m0, int n0, f32x4 acc[4][4])
{
  __shared__ short As[128*32];   // [row][k] linear, row stride 64 B
  __shared__ short Bs[128*32];
  const int tid = threadIdx.x;
  const int wv = tid >> 6, l = tid & 63;
  const int lr = l & 15, kq = l >> 4;
  const int wr = wv >> 1, wc = wv & 1;
#pragma unroll
  for (int i=0;i<4;i++)
#pragma unroll
    for (int j=0;j<4;j++) acc[i][j] = (f32x4){0.f,0.f,0.f,0.f};

  const int srow = wv*16 + (l>>2);
  const int skb  = (l&3)*16;
  char* Asb = (char*)As;
  char* Bsb = (char*)Bs;

  for (int k0=0; k0<K; k0+=32){
    const bf16* Ap = A0; int ka = k0;
    if (SPLIT && k0 >= 512){ Ap = A1; ka = k0-512; }
    const char* ga = (const char*)(Ap + (long)(m0+srow)*lda + ka) + skb;
    const char* gw = (const char*)(W  + (long)(n0+srow)*ldw + k0) + skb;
    gld_lds16(ga,                   Asb + wv*1024);
    gld_lds16(ga + (long)64*lda*2,  Asb + 4096 + wv*1024);
    gld_lds16(gw,                   Bsb + wv*1024);
    gld_lds16(gw + (long)64*ldw*2,  Bsb + 4096 + wv*1024);
    __syncthreads();                 // drains vmcnt (async LDS loads) + lgkm
    bf16x8 af[4], bw[4];
#pragma unroll
    for (int i=0;i<4;i++){
      af[i] = *(const bf16x8*)(Asb + (wr*64 + i*16 + lr)*64 + kq*16);
      bw[i] = *(const bf16x8*)(Bsb + (wc*64 + i*16 + lr)*64 + kq*16);
    }
#pragma unroll
    for (int i=0;i<4;i++)
#pragma unroll
      for (int j=0;j<4;j++)
        acc[i][j] = __builtin_amdgcn_mfma_f32_16x16x32_bf16(bw[i], af[j], acc[i][j], 0, 0, 0);
    __syncthreads();                 // protect LDS from next stage overwrite
  }
}

// ---- prep ---------------------------------------------------------------
extern "C" __global__ void k_prep_row(const int* __restrict__ preds,
                                      const float* __restrict__ matrix,
                                      float* __restrict__ rowb)
{
  int idx = blockIdx.x*256 + threadIdx.x;
  if (idx >= R_*C_) return;
  int r = idx / C_;
  int c = idx - r*C_;
  int s0 = preds[2*r], s1 = preds[2*r+1];
  rowb[idx] = matrix[((long)s0*NOBJ_ + s1)*C_ + c];
}

extern "C" __global__ void k_prep_weff(const float* __restrict__ w3w,
                                       const float* __restrict__ w4w,
                                       const float* __restrict__ w5w,
                                       bf16* __restrict__ weffb)
{
  int idx = blockIdx.x*256 + threadIdx.x;        // 3*512*512
  if (idx >= 3*512*512) return;
  int g   = idx >> 18;
  int rem = idx & 0x3FFFF;
  int o   = rem >> 9;
  int k   = rem & 511;
  const float* w = (g==0) ? w3w : (g==1) ? w4w : w5w;
  weffb[idx] = __float2bfloat16(w[o*1024 + k] + w[o*1024 + 512 + k]);
}

extern "C" __global__ void k_f2b(const float* __restrict__ s,
                                 bf16* __restrict__ d, int n)
{
  int i = (blockIdx.x*256 + threadIdx.x)*8;
  if (i >= n) return;
  float4 v0 = *(const float4*)(s+i);
  float4 v1 = *(const float4*)(s+i+4);
  bf16x8 o;
  o[0]=f2bs(v0.x); o[1]=f2bs(v0.y); o[2]=f2bs(v0.z); o[3]=f2bs(v0.w);
  o[4]=f2bs(v1.x); o[5]=f2bs(v1.y); o[6]=f2bs(v1.z); o[7]=f2bs(v1.w);
  *(bf16x8*)((short*)d + i) = o;
}

// wc[51][27136] -> wcT[27136][64] (cols 51..63 zero), tile-transposed via LDS
extern "C" __global__ void __launch_bounds__(256)
k_wct(const float* __restrict__ wc, float* __restrict__ wcT)
{
  __shared__ float sm[C_][65];
  int k0 = blockIdx.x * 64;
  int t = threadIdx.x;
  for (int idx = t; idx < C_*64; idx += 256){
    int c = idx >> 6, k = idx & 63;
    sm[c][k] = wc[(long)c*K27_ + k0 + k];
  }
  __syncthreads();
  for (int idx = t; idx < 64*64; idx += 256){
    int k = idx >> 6, c = idx & 63;
    wcT[(long)(k0+k)*64 + c] = (c < C_) ? sm[c][k] : 0.f;
  }
}

// ---- per-iteration: a1 = row . h[2:], s = h0+h1 (bf16, vectorized) ------
// 4 r per block; 64 threads (one wave) per r; 8 cols per thread.
extern "C" __global__ void __launch_bounds__(256)
k_as1(const bf16* __restrict__ fh, const float* __restrict__ rowb,
      bf16* __restrict__ as1b)
{
  int t = threadIdx.x;
  int r  = blockIdx.x*4 + (t>>6);          // wave-uniform
  int cl = (t&63)*8;
  const short* h  = (const short*)fh + (size_t)r*NODE_*512;
  const float* rw = rowb + r*C_;
  bf16x8 v0 = *(const bf16x8*)(h + cl);
  bf16x8 v1 = *(const bf16x8*)(h + 512 + cl);
  float a[8], s[8];
#pragma unroll
  for (int k=0;k<8;k++){ s[k] = b2f(v0[k]) + b2f(v1[k]); a[k] = 0.f; }
#pragma unroll 17
  for (int c=0;c<C_;c++){
    bf16x8 v = *(const bf16x8*)(h + (2+c)*512 + cl);
    float w = rw[c];
#pragma unroll
    for (int k=0;k<8;k++) a[k] = fmaf(w, b2f(v[k]), a[k]);
  }
  bf16x8 oa, os;
#pragma unroll
  for (int k=0;k<8;k++){ oa[k] = f2bs(a[k]); os[k] = f2bs(s[k]); }
  *(bf16x8*)((short*)as1b + (size_t)(2*r  )*512 + cl) = oa;
  *(bf16x8*)((short*)as1b + (size_t)(2*r+1)*512 + cl) = os;
}

// ---- UT = as1 @ WeffAll.T : (4096,512)@(512,1536), fp32 out -------------
extern "C" __global__ void __launch_bounds__(256)
k_gemm_ut(const bf16* __restrict__ as1b, const bf16* __restrict__ weffb,
          float* __restrict__ UT)
{
  const int nnt = 1536/128;                // 12
  int lid = xcd_swz(blockIdx.x, gridDim.x);
  int m0 = (lid / nnt) * 128;
  int n0 = (lid % nnt) * 128;
  f32x4 acc[4][4];
  mfma_core<false>(as1b, nullptr, weffb, 512, 512, 512, m0, n0, acc);
  const int wv = threadIdx.x >> 6, l = threadIdx.x & 63;
  const int wr = wv >> 1, wc = wv & 1;
  const int q4 = (l>>4)*4, lc = l & 15;
#pragma unroll
  for (int j=0;j<4;j++){
    int rn = m0 + wr*64 + j*16 + lc;
#pragma unroll
    for (int i=0;i<4;i++){
      int og = n0 + wc*64 + i*16 + q4;
      *(f32x4*)&UT[(size_t)rn*1536 + og] = acc[i][j];
    }
  }
}

// ---- stage Z/R: acc = fh @ {w3u|w4u}.T + UT-term, fused epilogue --------
extern "C" __global__ void __launch_bounds__(256)
k_gemm_zr(const bf16* __restrict__ fh, const bf16* __restrict__ wub,
          const float* __restrict__ UT, const float* __restrict__ rowb,
          const float* __restrict__ b3w, const float* __restrict__ b3u,
          const float* __restrict__ b4w, const float* __restrict__ b4u,
          bf16* __restrict__ zvb, bf16* __restrict__ gb)
{
  const int nnt = 1024/128;                // 8 (o 0-511: z, 512-1023: r)
  int lid = xcd_swz(blockIdx.x, gridDim.x);
  int m0 = (lid / nnt) * 128;
  int n0 = (lid % nnt) * 128;
  f32x4 acc[4][4];
  mfma_core<false>(fh, nullptr, wub, 512, 512, 512, m0, n0, acc);

  const int wv = threadIdx.x >> 6, l = threadIdx.x & 63;
  const int wr = wv >> 1, wc = wv & 1;
  const int q4 = (l>>4)*4, lc = l & 15;
  const int side = n0 >> 9;                // block-uniform
  const float* bW = side ? b4w : b3w;
  const float* bU = side ? b4u : b3u;

  int rnj[4]; float scj[4]; const float* utj[4];
#pragma unroll
  for (int j=0;j<4;j++){
    int rn = m0 + wr*64 + j*16 + lc;
    int r  = rn / 53, nd = rn - r*53;
    rnj[j] = rn;
    scj[j] = (nd<2) ? 1.f : rowb[r*C_ + nd - 2];
    utj[j] = UT + (size_t)(2*r + ((nd<2)?0:1))*1536;
  }
#pragma unroll
  for (int i=0;i<4;i++){
    int og = n0 + wc*64 + i*16 + q4;       // 0..1023, %4==0; UT col = og
    int ol = og & 511;                     // output feature col
    float4 bWv = *(const float4*)&bW[ol];
    float4 bUv = *(const float4*)&bU[ol];
#pragma unroll
    for (int j=0;j<4;j++){
      f32x4 up = *(const f32x4*)(utj[j] + og);
      size_t idx = (size_t)rnj[j]*512 + ol;
      bf16x4 o4;
      if (side == 0){
#pragma unroll
        for (int rg=0; rg<4; rg++){
          float v = acc[i][j][rg] + scj[j]*up[rg]
                  + ((const float*)&bWv)[rg] + ((const float*)&bUv)[rg];
          o4[rg] = f2bs(sigmoidf_(v));
        }
        *(bf16x4*)((short*)zvb + idx) = o4;
      } else {
        bf16x4 f4 = *(const bf16x4*)((const short*)fh + idx);
#pragma unroll
        for (int rg=0; rg<4; rg++){
          float v = acc[i][j][rg] + scj[j]*up[rg]
                  + ((const float*)&bWv)[rg] + ((const float*)&bUv)[rg];
          o4[rg] = f2bs(sigmoidf_(v) * b2f(f4[rg]));
        }
        *(bf16x4*)((short*)gb + idx) = o4;
      }
    }
  }
}

// ---- stage H: acc = g @ w5u.T, epilogue -> h update (in-place bf16) -----
extern "C" __global__ void __launch_bounds__(256)
k_gemm_h(const bf16* __restrict__ gbuf, const bf16* __restrict__ w5ub,
         const float* __restrict__ UT,  const float* __restrict__ rowb,
         const float* __restrict__ b5w, const float* __restrict__ b5u,
         const bf16* __restrict__ zvb,  const bf16* __restrict__ fh_in,
         bf16* __restrict__ hb)
{
  const int nnt = 512/128;                 // 4
  int lid = xcd_swz(blockIdx.x, gridDim.x);
  int m0 = (lid / nnt) * 128;
  int n0 = (lid % nnt) * 128;
  f32x4 acc[4][4];
  mfma_core<false>(gbuf, nullptr, w5ub, 512, 512, 512, m0, n0, acc);

  const int wv = threadIdx.x >> 6, l = threadIdx.x & 63;
  const int wr = wv >> 1, wc = wv & 1;
  const int q4 = (l>>4)*4, lc = l & 15;

  int rnj[4]; float scj[4]; const float* utj[4];
#pragma unroll
  for (int j=0;j<4;j++){
    int rn = m0 + wr*64 + j*16 + lc;
    int r  = rn / 53, nd = rn - r*53;
    rnj[j] = rn;
    scj[j] = (nd<2) ? 1.f : rowb[r*C_ + nd - 2];
    utj[j] = UT + (size_t)(2*r + ((nd<2)?0:1))*1536 + 1024;
  }
#pragma unroll
  for (int i=0;i<4;i++){
    int og = n0 + wc*64 + i*16 + q4;       // 0..511
    float4 b5wv = *(const float4*)&b5w[og];
    float4 b5uv = *(const float4*)&b5u[og];
#pragma unroll
    for (int j=0;j<4;j++){
      f32x4 up = *(const f32x4*)(utj[j] + og);
      size_t idx = (size_t)rnj[j]*512 + og;
      bf16x4 z4 = *(const bf16x4*)((const short*)zvb   + idx);
      bf16x4 f4 = *(const bf16x4*)((const short*)fh_in + idx);
      bf16x4 o4;
#pragma unroll
      for (int rg=0; rg<4; rg++){
        float hv = tanhf_(acc[i][j][rg] + scj[j]*up[rg]
                 + ((const float*)&b5wv)[rg] + ((const float*)&b5uv)[rg]);
        float z  = b2f(z4[rg]);
        o4[rg] = f2bs((1.f - z)*b2f(f4[rg]) + z*hv);
      }
      *(bf16x4*)((short*)hb + idx) = o4;
    }
  }
}

// ---- output: out_lin = relu([h | input] @ wo.T + bo), fp32 out ----------
extern "C" __global__ void __launch_bounds__(256)
k_gemm_o(const bf16* __restrict__ hb, const bf16* __restrict__ inb,
         const bf16* __restrict__ wob, const float* __restrict__ bo,
         float* __restrict__ outl)
{
  const int nnt = 512/128;                 // 4
  int lid = xcd_swz(blockIdx.x, gridDim.x);
  int m0 = (lid / nnt) * 128;
  int n0 = (lid % nnt) * 128;
  f32x4 acc[4][4];
  mfma_core<true>(hb, inb, wob, 512, 1024, 1024, m0, n0, acc);

  const int wv = threadIdx.x >> 6, l = threadIdx.x & 63;
  const int wr = wv >> 1, wc = wv & 1;
  const int q4 = (l>>4)*4, lc = l & 15;
#pragma unroll
  for (int i=0;i<4;i++){
    int og = n0 + wc*64 + i*16 + q4;
    float4 bv = *(const float4*)&bo[og];
#pragma unroll
    for (int j=0;j<4;j++){
      int rn = m0 + wr*64 + j*16 + lc;
      f32x4 o;
#pragma unroll
      for (int rg=0; rg<4; rg++)
        o[rg] = fmaxf(acc[i][j][rg] + ((const float*)&bv)[rg], 0.f);
      *(f32x4*)&outl[(size_t)rn*512 + og] = o;
    }
  }
}

// ---- rel_dists = out_lin.reshape(R,27136) @ wc.T + bc -------------------
extern "C" __global__ void k_rel_init(const float* __restrict__ bc,
                                      float* __restrict__ dout)
{
  int idx = blockIdx.x*256 + threadIdx.x;
  if (idx >= R_*C_) return;
  dout[idx] = bc[idx % C_];
}

// fp32 LDS-tiled: block = 32 rows x 64-k steps, 8 k-chunks (y). Each thread
// owns 4 rows x 2 cols.
#define RELKCH (K27_/8)   // 3392 = 53*64
extern "C" __global__ void __launch_bounds__(256)
k_rel_gemm(const float* __restrict__ outl, const float* __restrict__ wcT,
           float* __restrict__ dout)
{
  __shared__ float As[32][68];
  __shared__ float Ws[64][64];
  const int r0    = blockIdx.x * 32;
  const int kbase = blockIdx.y * RELKCH;
  const int t  = threadIdx.x;
  const int c0 = (t & 31) * 2;
  const int rg = t >> 5;                   // 0..7 -> rows rg*4..rg*4+3
  float acc[4][2];
#pragma unroll
  for (int i=0;i<4;i++){ acc[i][0]=0.f; acc[i][1]=0.f; }

  for (int k0=0; k0<RELKCH; k0+=64){
    __syncthreads();
#pragma unroll
    for (int i=0;i<8;i++){                 // A: 32x64 = 2048 f4, 8/thread
      int f4  = i*256 + t;
      int row = f4 >> 4;
      int kf  = (f4 & 15) << 2;
      float4 v = *(const float4*)(outl + (long)(r0+row)*K27_ + kbase + k0 + kf);
      *(float4*)&As[row][kf] = v;
    }
#pragma unroll
    for (int i=0;i<4;i++){                 // W: 64x64 = 1024 f4, 4/thread
      int f4 = i*256 + t;
      int kk = f4 >> 4;
      int cf = (f4 & 15) << 2;
      *(float4*)&Ws[kk][cf] = *(const float4*)(wcT + (long)(kbase+k0+kk)*64 + cf);
    }
    __syncthreads();
#pragma unroll
    for (int k=0;k<64;k+=4){
      float4 a0 = *(const float4*)&As[rg*4+0][k];
      float4 a1 = *(const float4*)&As[rg*4+1][k];
      float4 a2 = *(const float4*)&As[rg*4+2][k];
      float4 a3 = *(const float4*)&As[rg*4+3][k];
#pragma unroll
      for (int j=0;j<4;j++){
        float2 w = *(const float2*)&Ws[k+j][c0];
        float aj0 = (&a0.x)[j], aj1 = (&a1.x)[j], aj2 = (&a2.x)[j], aj3 = (&a3.x)[j];
        acc[0][0] = fmaf(aj0, w.x, acc[0][0]);
        acc[0][1] = fmaf(aj0, w.y, acc[0][1]);
        acc[1][0] = fmaf(aj1, w.x, acc[1][0]);
        acc[1][1] = fmaf(aj1, w.y, acc[1][1]);
        acc[2][0] = fmaf(aj2, w.x, acc[2][0]);
        acc[2][1] = fmaf(aj2, w.y, acc[2][1]);
        acc[3][0] = fmaf(aj3, w.x, acc[3][0]);
        acc[3][1] = fmaf(aj3, w.y, acc[3][1]);
      }
    }
  }
#pragma unroll
  for (int i=0;i<4;i++){
    int m = r0 + rg*4 + i;
    if (c0   < C_) atomicAdd(&dout[m*C_ + c0  ], acc[i][0]);
    if (c0+1 < C_) atomicAdd(&dout[m*C_ + c0+1], acc[i][1]);
  }
}

// -------------------------------------------------------------------------
extern "C" void kernel_launch(void* const* d_in, const int* in_sizes, int n_in,
                              void* d_out, int out_size, void* d_ws, size_t ws_size,
                              hipStream_t stream)
{
  const int*   preds = (const int*)  d_in[1];
  const float* input = (const float*)d_in[2];
  const float* matrix= (const float*)d_in[4];
  const float* w3w=(const float*)d_in[5],  *b3w=(const float*)d_in[6];
  const float* w3u=(const float*)d_in[7],  *b3u=(const float*)d_in[8];
  const float* w4w=(const float*)d_in[9],  *b4w=(const float*)d_in[10];
  const float* w4u=(const float*)d_in[11], *b4u=(const float*)d_in[12];
  const float* w5w=(const float*)d_in[13], *b5w=(const float*)d_in[14];
  const float* w5u=(const float*)d_in[15], *b5u=(const float*)d_in[16];
  const float* wo =(const float*)d_in[17], *bo =(const float*)d_in[18];
  const float* wc =(const float*)d_in[19], *bc =(const float*)d_in[20];
  float* dout = (float*)d_out;

  char* ws = (char*)d_ws;
  size_t off = 0;
  auto alloc = [&](size_t bytes){
    void* p = ws + off;
    off += (bytes + 255) & ~(size_t)255;
    return p;
  };
  bf16*  hb    = (bf16*) alloc((size_t)RN_*512*2);     // 111 MB
  bf16*  inb   = (bf16*) alloc((size_t)RN_*512*2);     // 111 MB
  bf16*  zvb   = (bf16*) alloc((size_t)RN_*512*2);     // 111 MB  (adjacent..
  bf16*  gb    = (bf16*) alloc((size_t)RN_*512*2);     // 111 MB   ..to zvb)
  bf16*  as1b  = (bf16*) alloc((size_t)4096*512*2);
  float* UT    = (float*)alloc((size_t)4096*1536*4);   // 25 MB
  float* rowb  = (float*)alloc((size_t)R_*C_*4);
  float* wcT   = (float*)alloc((size_t)K27_*64*4);     // 6.9 MB
  bf16*  weffb = (bf16*) alloc((size_t)1536*512*2);
  bf16*  wub   = (bf16*) alloc((size_t)1024*512*2);    // [w3u ; w4u]
  bf16*  w5ub  = (bf16*) alloc((size_t)512*512*2);
  bf16*  wob   = (bf16*) alloc((size_t)512*1024*2);
  // outl (fp32, 222 MB) aliases zvb+gb (both dead once the T loop finishes;
  // the two bf16 allocs are contiguous and 256B-aligned).
  float* outl  = (float*)zvb;

  // prep
  k_prep_row <<<(R_*C_+255)/256, 256, 0, stream>>>(preds, matrix, rowb);
  k_prep_weff<<<(3*512*512)/256, 256, 0, stream>>>(w3w, w4w, w5w, weffb);
  k_wct<<<K27_/64, 256, 0, stream>>>(wc, wcT);
  k_f2b<<<((RN_*512/8)+255)/256, 256, 0, stream>>>(input, inb, RN_*512);
  k_f2b<<<((512*512/8)+255)/256, 256, 0, stream>>>(w3u, wub, 512*512);
  k_f2b<<<((512*512/8)+255)/256, 256, 0, stream>>>(w4u, wub + 512*512, 512*512);
  k_f2b<<<((512*512/8)+255)/256, 256, 0, stream>>>(w5u, w5ub, 512*512);
  k_f2b<<<((512*1024/8)+255)/256, 256, 0, stream>>>(wo, wob, 512*1024);

  for (int t=0;t<3;t++){
    const bf16* fh = (t==0) ? inb : hb;
    k_as1    <<<R_/4, 256, 0, stream>>>(fh, rowb, as1b);
    k_gemm_ut<<<(4096/128)*(1536/128), 256, 0, stream>>>(as1b, weffb, UT);
    k_gemm_zr<<<(RN_/128)*(1024/128), 256, 0, stream>>>(fh, wub, UT, rowb,
                                                        b3w,b3u,b4w,b4u, zvb, gb);
    k_gemm_h <<<(RN_/128)*(512/128), 256, 0, stream>>>(gb, w5ub, UT, rowb,
                                                       b5w, b5u, zvb, fh, hb);
  }
  k_gemm_o  <<<(RN_/128)*(512/128), 256, 0, stream>>>(hb, inb, wob, bo, outl);
  k_rel_init<<<(R_*C_+255)/256, 256, 0, stream>>>(bc, dout);
  k_rel_gemm<<<dim3(R_/32, 8), 256, 0, stream>>>(outl, wcT, dout);
}

// Round 7
// 2324.716 us; speedup vs baseline: 4.0884x; 1.0613x over previous
//
#include <hip/hip_runtime.h>
#include <hip/hip_bf16.h>
#include <math.h>

// GGNNRel forward, round 7: T3 minimum 2-phase double-buffered K-loop in
// mfma_core (STAGE next tile BEFORE ds_read+MFMA of current; ONE barrier per
// K-step whose implicit vmcnt(0) drains the prefetch). Everything else
// byte-identical to round 6 (swapped-operand epilogues, 320us zr).
//
// Algebraic identities (round 1, verified): av1 rows = row[r]@h[2:];
// av2 = outer(row, h0+h1); concat([av,av],-1)@W.T == av@(W[:,:512]+W[:,512:]).T
// => per gate g: u_g = a1@Weff_g.T, t_g = s@Weff_g.T; node<2 -> u_g,
//    node>=2 -> row[r,node-2]*t_g  (UT buffer, added in GEMM epilogues).

#define R_    2048
#define NODE_ 53
#define C_    51
#define NOBJ_ 151
#define RN_   (R_*NODE_)    // 108544 = 128*848
#define K27_  (NODE_*512)   // 27136

typedef __hip_bfloat16 bf16;
typedef __attribute__((ext_vector_type(8))) short bf16x8;
typedef __attribute__((ext_vector_type(4))) short bf16x4;
typedef __attribute__((ext_vector_type(4))) float f32x4;

__device__ __forceinline__ float sigmoidf_(float x){ return 1.f/(1.f+__expf(-x)); }
__device__ __forceinline__ float tanhf_(float x){ return 2.f/(1.f+__expf(-2.f*x)) - 1.f; }
__device__ __forceinline__ float b2f(short s){
  union{float f; unsigned u;} x; x.u = ((unsigned)(unsigned short)s)<<16; return x.f;
}
__device__ __forceinline__ short f2bs(float f){
  __hip_bfloat16 h = __float2bfloat16(f);
  return *reinterpret_cast<short*>(&h);
}

// XCD-aware swizzle (all grids %8==0): contiguous m-major chunk per XCD.
__device__ __forceinline__ int xcd_swz(int bid, int nwg){
  int chunk = nwg >> 3;
  return (bid & 7) * chunk + (bid >> 3);
}

__device__ __forceinline__ void gld_lds16(const void* g, void* l){
  __builtin_amdgcn_global_load_lds(
      (const __attribute__((address_space(1))) void*)g,
      (__attribute__((address_space(3))) void*)l, 16, 0, 0);
}

// acc[i][j] = sum_k W[o][k]*A[rn][k] with SWAPPED operands:
//   D row-dim = o  : og = n0 + wc*64 + i*16 + (l>>4)*4 + rg
//   D col-dim = rn : rn = m0 + wr*64 + j*16 + (l&15)
// A row-major (M=rn, lda), W row-major (N=o, ldw), both bf16.
// SPLIT: A switches A0->A1 at k==512 (output-stage concat).
// Double-buffered (T3 2-phase): stage(k+1) issued before compute(k); single
// __syncthreads per step (implicit vmcnt(0) drains prefetch; MFMA's lgkmcnt
// guarantees all reads of buf[cur] done before the barrier -> next-iter stage
// into it is race-free).
template<bool SPLIT>
__device__ __forceinline__ void mfma_core(const bf16* __restrict__ A0,
                                          const bf16* __restrict__ A1,
                                          const bf16* __restrict__ W,
                                          int lda, int ldw, int K,
                                          int m0, int n0, f32x4 acc[4][4])
{
  __shared__ short lds[2][2*128*32];   // [buf][A 128x32 | B 128x32], 32 KB
  const int tid = threadIdx.x;
  const int wv = tid >> 6, l = tid & 63;
  const int lr = l & 15, kq = l >> 4;
  const int wr = wv >> 1, wc = wv & 1;
#pragma unroll
  for (int i=0;i<4;i++)
#pragma unroll
    for (int j=0;j<4;j++) acc[i][j] = (f32x4){0.f,0.f,0.f,0.f};

  const int srow = wv*16 + (l>>2);
  const int skb  = (l&3)*16;

  auto stage = [&](int b, int k0){
    const bf16* Ap = A0; int ka = k0;
    if (SPLIT && k0 >= 512){ Ap = A1; ka = k0-512; }
    const char* ga = (const char*)(Ap + (long)(m0+srow)*lda + ka) + skb;
    const char* gw = (const char*)(W  + (long)(n0+srow)*ldw + k0) + skb;
    char* Asb = (char*)lds[b];
    char* Bsb = (char*)lds[b] + 8192;
    gld_lds16(ga,                   Asb + wv*1024);
    gld_lds16(ga + (long)64*lda*2,  Asb + 4096 + wv*1024);
    gld_lds16(gw,                   Bsb + wv*1024);
    gld_lds16(gw + (long)64*ldw*2,  Bsb + 4096 + wv*1024);
  };

  stage(0, 0);
  __syncthreads();                   // drains prologue loads + barrier
  int cur = 0;
  for (int k0=0; k0<K; k0+=32){
    if (k0+32 < K) stage(cur^1, k0+32);   // prefetch next tile (async)
    const char* Asb = (const char*)lds[cur];
    const char* Bsb = (const char*)lds[cur] + 8192;
    bf16x8 af[4], bw[4];
#pragma unroll
    for (int i=0;i<4;i++){
      af[i] = *(const bf16x8*)(Asb + (wr*64 + i*16 + lr)*64 + kq*16);
      bw[i] = *(const bf16x8*)(Bsb + (wc*64 + i*16 + lr)*64 + kq*16);
    }
#pragma unroll
    for (int i=0;i<4;i++)
#pragma unroll
      for (int j=0;j<4;j++)
        acc[i][j] = __builtin_amdgcn_mfma_f32_16x16x32_bf16(bw[i], af[j], acc[i][j], 0, 0, 0);
    __syncthreads();                 // vmcnt(0): prefetch landed; all reads of cur done
    cur ^= 1;
  }
}

// ---- prep ---------------------------------------------------------------
extern "C" __global__ void k_prep_row(const int* __restrict__ preds,
                                      const float* __restrict__ matrix,
                                      float* __restrict__ rowb)
{
  int idx = blockIdx.x*256 + threadIdx.x;
  if (idx >= R_*C_) return;
  int r = idx / C_;
  int c = idx - r*C_;
  int s0 = preds[2*r], s1 = preds[2*r+1];
  rowb[idx] = matrix[((long)s0*NOBJ_ + s1)*C_ + c];
}

extern "C" __global__ void k_prep_weff(const float* __restrict__ w3w,
                                       const float* __restrict__ w4w,
                                       const float* __restrict__ w5w,
                                       bf16* __restrict__ weffb)
{
  int idx = blockIdx.x*256 + threadIdx.x;        // 3*512*512
  if (idx >= 3*512*512) return;
  int g   = idx >> 18;
  int rem = idx & 0x3FFFF;
  int o   = rem >> 9;
  int k   = rem & 511;
  const float* w = (g==0) ? w3w : (g==1) ? w4w : w5w;
  weffb[idx] = __float2bfloat16(w[o*1024 + k] + w[o*1024 + 512 + k]);
}

extern "C" __global__ void k_f2b(const float* __restrict__ s,
                                 bf16* __restrict__ d, int n)
{
  int i = (blockIdx.x*256 + threadIdx.x)*8;
  if (i >= n) return;
  float4 v0 = *(const float4*)(s+i);
  float4 v1 = *(const float4*)(s+i+4);
  bf16x8 o;
  o[0]=f2bs(v0.x); o[1]=f2bs(v0.y); o[2]=f2bs(v0.z); o[3]=f2bs(v0.w);
  o[4]=f2bs(v1.x); o[5]=f2bs(v1.y); o[6]=f2bs(v1.z); o[7]=f2bs(v1.w);
  *(bf16x8*)((short*)d + i) = o;
}

// wc[51][27136] -> wcT[27136][64] (cols 51..63 zero), tile-transposed via LDS
extern "C" __global__ void __launch_bounds__(256)
k_wct(const float* __restrict__ wc, float* __restrict__ wcT)
{
  __shared__ float sm[C_][65];
  int k0 = blockIdx.x * 64;
  int t = threadIdx.x;
  for (int idx = t; idx < C_*64; idx += 256){
    int c = idx >> 6, k = idx & 63;
    sm[c][k] = wc[(long)c*K27_ + k0 + k];
  }
  __syncthreads();
  for (int idx = t; idx < 64*64; idx += 256){
    int k = idx >> 6, c = idx & 63;
    wcT[(long)(k0+k)*64 + c] = (c < C_) ? sm[c][k] : 0.f;
  }
}

// ---- per-iteration: a1 = row . h[2:], s = h0+h1 (bf16, vectorized) ------
// 4 r per block; 64 threads (one wave) per r; 8 cols per thread.
extern "C" __global__ void __launch_bounds__(256)
k_as1(const bf16* __restrict__ fh, const float* __restrict__ rowb,
      bf16* __restrict__ as1b)
{
  int t = threadIdx.x;
  int r  = blockIdx.x*4 + (t>>6);          // wave-uniform
  int cl = (t&63)*8;
  const short* h  = (const short*)fh + (size_t)r*NODE_*512;
  const float* rw = rowb + r*C_;
  bf16x8 v0 = *(const bf16x8*)(h + cl);
  bf16x8 v1 = *(const bf16x8*)(h + 512 + cl);
  float a[8], s[8];
#pragma unroll
  for (int k=0;k<8;k++){ s[k] = b2f(v0[k]) + b2f(v1[k]); a[k] = 0.f; }
#pragma unroll 17
  for (int c=0;c<C_;c++){
    bf16x8 v = *(const bf16x8*)(h + (2+c)*512 + cl);
    float w = rw[c];
#pragma unroll
    for (int k=0;k<8;k++) a[k] = fmaf(w, b2f(v[k]), a[k]);
  }
  bf16x8 oa, os;
#pragma unroll
  for (int k=0;k<8;k++){ oa[k] = f2bs(a[k]); os[k] = f2bs(s[k]); }
  *(bf16x8*)((short*)as1b + (size_t)(2*r  )*512 + cl) = oa;
  *(bf16x8*)((short*)as1b + (size_t)(2*r+1)*512 + cl) = os;
}

// ---- UT = as1 @ WeffAll.T : (4096,512)@(512,1536), fp32 out -------------
extern "C" __global__ void __launch_bounds__(256)
k_gemm_ut(const bf16* __restrict__ as1b, const bf16* __restrict__ weffb,
          float* __restrict__ UT)
{
  const int nnt = 1536/128;                // 12
  int lid = xcd_swz(blockIdx.x, gridDim.x);
  int m0 = (lid / nnt) * 128;
  int n0 = (lid % nnt) * 128;
  f32x4 acc[4][4];
  mfma_core<false>(as1b, nullptr, weffb, 512, 512, 512, m0, n0, acc);
  const int wv = threadIdx.x >> 6, l = threadIdx.x & 63;
  const int wr = wv >> 1, wc = wv & 1;
  const int q4 = (l>>4)*4, lc = l & 15;
#pragma unroll
  for (int j=0;j<4;j++){
    int rn = m0 + wr*64 + j*16 + lc;
#pragma unroll
    for (int i=0;i<4;i++){
      int og = n0 + wc*64 + i*16 + q4;
      *(f32x4*)&UT[(size_t)rn*1536 + og] = acc[i][j];
    }
  }
}

// ---- stage Z/R: acc = fh @ {w3u|w4u}.T + UT-term, fused epilogue --------
extern "C" __global__ void __launch_bounds__(256)
k_gemm_zr(const bf16* __restrict__ fh, const bf16* __restrict__ wub,
          const float* __restrict__ UT, const float* __restrict__ rowb,
          const float* __restrict__ b3w, const float* __restrict__ b3u,
          const float* __restrict__ b4w, const float* __restrict__ b4u,
          bf16* __restrict__ zvb, bf16* __restrict__ gb)
{
  const int nnt = 1024/128;                // 8 (o 0-511: z, 512-1023: r)
  int lid = xcd_swz(blockIdx.x, gridDim.x);
  int m0 = (lid / nnt) * 128;
  int n0 = (lid % nnt) * 128;
  f32x4 acc[4][4];
  mfma_core<false>(fh, nullptr, wub, 512, 512, 512, m0, n0, acc);

  const int wv = threadIdx.x >> 6, l = threadIdx.x & 63;
  const int wr = wv >> 1, wc = wv & 1;
  const int q4 = (l>>4)*4, lc = l & 15;
  const int side = n0 >> 9;                // block-uniform
  const float* bW = side ? b4w : b3w;
  const float* bU = side ? b4u : b3u;

  int rnj[4]; float scj[4]; const float* utj[4];
#pragma unroll
  for (int j=0;j<4;j++){
    int rn = m0 + wr*64 + j*16 + lc;
    int r  = rn / 53, nd = rn - r*53;
    rnj[j] = rn;
    scj[j] = (nd<2) ? 1.f : rowb[r*C_ + nd - 2];
    utj[j] = UT + (size_t)(2*r + ((nd<2)?0:1))*1536;
  }
#pragma unroll
  for (int i=0;i<4;i++){
    int og = n0 + wc*64 + i*16 + q4;       // 0..1023, %4==0; UT col = og
    int ol = og & 511;                     // output feature col
    float4 bWv = *(const float4*)&bW[ol];
    float4 bUv = *(const float4*)&bU[ol];
#pragma unroll
    for (int j=0;j<4;j++){
      f32x4 up = *(const f32x4*)(utj[j] + og);
      size_t idx = (size_t)rnj[j]*512 + ol;
      bf16x4 o4;
      if (side == 0){
#pragma unroll
        for (int rg=0; rg<4; rg++){
          float v = acc[i][j][rg] + scj[j]*up[rg]
                  + ((const float*)&bWv)[rg] + ((const float*)&bUv)[rg];
          o4[rg] = f2bs(sigmoidf_(v));
        }
        *(bf16x4*)((short*)zvb + idx) = o4;
      } else {
        bf16x4 f4 = *(const bf16x4*)((const short*)fh + idx);
#pragma unroll
        for (int rg=0; rg<4; rg++){
          float v = acc[i][j][rg] + scj[j]*up[rg]
                  + ((const float*)&bWv)[rg] + ((const float*)&bUv)[rg];
          o4[rg] = f2bs(sigmoidf_(v) * b2f(f4[rg]));
        }
        *(bf16x4*)((short*)gb + idx) = o4;
      }
    }
  }
}

// ---- stage H: acc = g @ w5u.T, epilogue -> h update (in-place bf16) -----
extern "C" __global__ void __launch_bounds__(256)
k_gemm_h(const bf16* __restrict__ gbuf, const bf16* __restrict__ w5ub,
         const float* __restrict__ UT,  const float* __restrict__ rowb,
         const float* __restrict__ b5w, const float* __restrict__ b5u,
         const bf16* __restrict__ zvb,  const bf16* __restrict__ fh_in,
         bf16* __restrict__ hb)
{
  const int nnt = 512/128;                 // 4
  int lid = xcd_swz(blockIdx.x, gridDim.x);
  int m0 = (lid / nnt) * 128;
  int n0 = (lid % nnt) * 128;
  f32x4 acc[4][4];
  mfma_core<false>(gbuf, nullptr, w5ub, 512, 512, 512, m0, n0, acc);

  const int wv = threadIdx.x >> 6, l = threadIdx.x & 63;
  const int wr = wv >> 1, wc = wv & 1;
  const int q4 = (l>>4)*4, lc = l & 15;

  int rnj[4]; float scj[4]; const float* utj[4];
#pragma unroll
  for (int j=0;j<4;j++){
    int rn = m0 + wr*64 + j*16 + lc;
    int r  = rn / 53, nd = rn - r*53;
    rnj[j] = rn;
    scj[j] = (nd<2) ? 1.f : rowb[r*C_ + nd - 2];
    utj[j] = UT + (size_t)(2*r + ((nd<2)?0:1))*1536 + 1024;
  }
#pragma unroll
  for (int i=0;i<4;i++){
    int og = n0 + wc*64 + i*16 + q4;       // 0..511
    float4 b5wv = *(const float4*)&b5w[og];
    float4 b5uv = *(const float4*)&b5u[og];
#pragma unroll
    for (int j=0;j<4;j++){
      f32x4 up = *(const f32x4*)(utj[j] + og);
      size_t idx = (size_t)rnj[j]*512 + og;
      bf16x4 z4 = *(const bf16x4*)((const short*)zvb   + idx);
      bf16x4 f4 = *(const bf16x4*)((const short*)fh_in + idx);
      bf16x4 o4;
#pragma unroll
      for (int rg=0; rg<4; rg++){
        float hv = tanhf_(acc[i][j][rg] + scj[j]*up[rg]
                 + ((const float*)&b5wv)[rg] + ((const float*)&b5uv)[rg]);
        float z  = b2f(z4[rg]);
        o4[rg] = f2bs((1.f - z)*b2f(f4[rg]) + z*hv);
      }
      *(bf16x4*)((short*)hb + idx) = o4;
    }
  }
}

// ---- output: out_lin = relu([h | input] @ wo.T + bo), fp32 out ----------
extern "C" __global__ void __launch_bounds__(256)
k_gemm_o(const bf16* __restrict__ hb, const bf16* __restrict__ inb,
         const bf16* __restrict__ wob, const float* __restrict__ bo,
         float* __restrict__ outl)
{
  const int nnt = 512/128;                 // 4
  int lid = xcd_swz(blockIdx.x, gridDim.x);
  int m0 = (lid / nnt) * 128;
  int n0 = (lid % nnt) * 128;
  f32x4 acc[4][4];
  mfma_core<true>(hb, inb, wob, 512, 1024, 1024, m0, n0, acc);

  const int wv = threadIdx.x >> 6, l = threadIdx.x & 63;
  const int wr = wv >> 1, wc = wv & 1;
  const int q4 = (l>>4)*4, lc = l & 15;
#pragma unroll
  for (int i=0;i<4;i++){
    int og = n0 + wc*64 + i*16 + q4;
    float4 bv = *(const float4*)&bo[og];
#pragma unroll
    for (int j=0;j<4;j++){
      int rn = m0 + wr*64 + j*16 + lc;
      f32x4 o;
#pragma unroll
      for (int rg=0; rg<4; rg++)
        o[rg] = fmaxf(acc[i][j][rg] + ((const float*)&bv)[rg], 0.f);
      *(f32x4*)&outl[(size_t)rn*512 + og] = o;
    }
  }
}

// ---- rel_dists = out_lin.reshape(R,27136) @ wc.T + bc -------------------
extern "C" __global__ void k_rel_init(const float* __restrict__ bc,
                                      float* __restrict__ dout)
{
  int idx = blockIdx.x*256 + threadIdx.x;
  if (idx >= R_*C_) return;
  dout[idx] = bc[idx % C_];
}

// fp32 LDS-tiled: block = 32 rows x 64-k steps, 8 k-chunks (y). Each thread
// owns 4 rows x 2 cols.
#define RELKCH (K27_/8)   // 3392 = 53*64
extern "C" __global__ void __launch_bounds__(256)
k_rel_gemm(const float* __restrict__ outl, const float* __restrict__ wcT,
           float* __restrict__ dout)
{
  __shared__ float As[32][68];
  __shared__ float Ws[64][64];
  const int r0    = blockIdx.x * 32;
  const int kbase = blockIdx.y * RELKCH;
  const int t  = threadIdx.x;
  const int c0 = (t & 31) * 2;
  const int rg = t >> 5;                   // 0..7 -> rows rg*4..rg*4+3
  float acc[4][2];
#pragma unroll
  for (int i=0;i<4;i++){ acc[i][0]=0.f; acc[i][1]=0.f; }

  for (int k0=0; k0<RELKCH; k0+=64){
    __syncthreads();
#pragma unroll
    for (int i=0;i<8;i++){                 // A: 32x64 = 2048 f4, 8/thread
      int f4  = i*256 + t;
      int row = f4 >> 4;
      int kf  = (f4 & 15) << 2;
      float4 v = *(const float4*)(outl + (long)(r0+row)*K27_ + kbase + k0 + kf);
      *(float4*)&As[row][kf] = v;
    }
#pragma unroll
    for (int i=0;i<4;i++){                 // W: 64x64 = 1024 f4, 4/thread
      int f4 = i*256 + t;
      int kk = f4 >> 4;
      int cf = (f4 & 15) << 2;
      *(float4*)&Ws[kk][cf] = *(const float4*)(wcT + (long)(kbase+k0+kk)*64 + cf);
    }
    __syncthreads();
#pragma unroll
    for (int k=0;k<64;k+=4){
      float4 a0 = *(const float4*)&As[rg*4+0][k];
      float4 a1 = *(const float4*)&As[rg*4+1][k];
      float4 a2 = *(const float4*)&As[rg*4+2][k];
      float4 a3 = *(const float4*)&As[rg*4+3][k];
#pragma unroll
      for (int j=0;j<4;j++){
        float2 w = *(const float2*)&Ws[k+j][c0];
        float aj0 = (&a0.x)[j], aj1 = (&a1.x)[j], aj2 = (&a2.x)[j], aj3 = (&a3.x)[j];
        acc[0][0] = fmaf(aj0, w.x, acc[0][0]);
        acc[0][1] = fmaf(aj0, w.y, acc[0][1]);
        acc[1][0] = fmaf(aj1, w.x, acc[1][0]);
        acc[1][1] = fmaf(aj1, w.y, acc[1][1]);
        acc[2][0] = fmaf(aj2, w.x, acc[2][0]);
        acc[2][1] = fmaf(aj2, w.y, acc[2][1]);
        acc[3][0] = fmaf(aj3, w.x, acc[3][0]);
        acc[3][1] = fmaf(aj3, w.y, acc[3][1]);
      }
    }
  }
#pragma unroll
  for (int i=0;i<4;i++){
    int m = r0 + rg*4 + i;
    if (c0   < C_) atomicAdd(&dout[m*C_ + c0  ], acc[i][0]);
    if (c0+1 < C_) atomicAdd(&dout[m*C_ + c0+1], acc[i][1]);
  }
}

// -------------------------------------------------------------------------
extern "C" void kernel_launch(void* const* d_in, const int* in_sizes, int n_in,
                              void* d_out, int out_size, void* d_ws, size_t ws_size,
                              hipStream_t stream)
{
  const int*   preds = (const int*)  d_in[1];
  const float* input = (const float*)d_in[2];
  const float* matrix= (const float*)d_in[4];
  const float* w3w=(const float*)d_in[5],  *b3w=(const float*)d_in[6];
  const float* w3u=(const float*)d_in[7],  *b3u=(const float*)d_in[8];
  const float* w4w=(const float*)d_in[9],  *b4w=(const float*)d_in[10];
  const float* w4u=(const float*)d_in[11], *b4u=(const float*)d_in[12];
  const float* w5w=(const float*)d_in[13], *b5w=(const float*)d_in[14];
  const float* w5u=(const float*)d_in[15], *b5u=(const float*)d_in[16];
  const float* wo =(const float*)d_in[17], *bo =(const float*)d_in[18];
  const float* wc =(const float*)d_in[19], *bc =(const float*)d_in[20];
  float* dout = (float*)d_out;

  char* ws = (char*)d_ws;
  size_t off = 0;
  auto alloc = [&](size_t bytes){
    void* p = ws + off;
    off += (bytes + 255) & ~(size_t)255;
    return p;
  };
  bf16*  hb    = (bf16*) alloc((size_t)RN_*512*2);     // 111 MB
  bf16*  inb   = (bf16*) alloc((size_t)RN_*512*2);     // 111 MB
  bf16*  zvb   = (bf16*) alloc((size_t)RN_*512*2);     // 111 MB  (adjacent..
  bf16*  gb    = (bf16*) alloc((size_t)RN_*512*2);     // 111 MB   ..to zvb)
  bf16*  as1b  = (bf16*) alloc((size_t)4096*512*2);
  float* UT    = (float*)alloc((size_t)4096*1536*4);   // 25 MB
  float* rowb  = (float*)alloc((size_t)R_*C_*4);
  float* wcT   = (float*)alloc((size_t)K27_*64*4);     // 6.9 MB
  bf16*  weffb = (bf16*) alloc((size_t)1536*512*2);
  bf16*  wub   = (bf16*) alloc((size_t)1024*512*2);    // [w3u ; w4u]
  bf16*  w5ub  = (bf16*) alloc((size_t)512*512*2);
  bf16*  wob   = (bf16*) alloc((size_t)512*1024*2);
  // outl (fp32, 222 MB) aliases zvb+gb (both dead once the T loop finishes;
  // the two bf16 allocs are contiguous and 256B-aligned).
  float* outl  = (float*)zvb;

  // prep
  k_prep_row <<<(R_*C_+255)/256, 256, 0, stream>>>(preds, matrix, rowb);
  k_prep_weff<<<(3*512*512)/256, 256, 0, stream>>>(w3w, w4w, w5w, weffb);
  k_wct<<<K27_/64, 256, 0, stream>>>(wc, wcT);
  k_f2b<<<((RN_*512/8)+255)/256, 256, 0, stream>>>(input, inb, RN_*512);
  k_f2b<<<((512*512/8)+255)/256, 256, 0, stream>>>(w3u, wub, 512*512);
  k_f2b<<<((512*512/8)+255)/256, 256, 0, stream>>>(w4u, wub + 512*512, 512*512);
  k_f2b<<<((512*512/8)+255)/256, 256, 0, stream>>>(w5u, w5ub, 512*512);
  k_f2b<<<((512*1024/8)+255)/256, 256, 0, stream>>>(wo, wob, 512*1024);

  for (int t=0;t<3;t++){
    const bf16* fh = (t==0) ? inb : hb;
    k_as1    <<<R_/4, 256, 0, stream>>>(fh, rowb, as1b);
    k_gemm_ut<<<(4096/128)*(1536/128), 256, 0, stream>>>(as1b, weffb, UT);
    k_gemm_zr<<<(RN_/128)*(1024/128), 256, 0, stream>>>(fh, wub, UT, rowb,
                                                        b3w,b3u,b4w,b4u, zvb, gb);
    k_gemm_h <<<(RN_/128)*(512/128), 256, 0, stream>>>(gb, w5ub, UT, rowb,
                                                       b5w, b5u, zvb, fh, hb);
  }
  k_gemm_o  <<<(RN_/128)*(512/128), 256, 0, stream>>>(hb, inb, wob, bo, outl);
  k_rel_init<<<(R_*C_+255)/256, 256, 0, stream>>>(bc, dout);
  k_rel_gemm<<<dim3(R_/32, 8), 256, 0, stream>>>(outl, wcT, dout);
}